// Round 6
// baseline (3337.785 us; speedup 1.0000x reference)
//
#include <hip/hip_runtime.h>
#include <cfloat>
#include <cmath>

// ---------------------------------------------------------------------------
// Round 5: co-blocked fp32 encoder convs (TCO output channels per thread).
// Each staged input plane is reused TCO times -> L2 traffic / TCO, FMA density
// up ~TCO x. Accumulation order per output unchanged => latent bit-identical
// => VQ indices identical. dec1-4 MFMA path unchanged from R4.
// ---------------------------------------------------------------------------

using f32x4  = __attribute__((ext_vector_type(4))) float;
using bf16x8 = __attribute__((ext_vector_type(8))) short;
typedef float f32x4u __attribute__((ext_vector_type(4), aligned(4)));  // 4B-aligned vec load

__device__ __forceinline__ unsigned short f32_to_bf16(float f) {
    unsigned int u = __float_as_uint(f);
    u += 0x7fffu + ((u >> 16) & 1u);          // round-to-nearest-even
    return (unsigned short)(u >> 16);
}
__device__ __forceinline__ void store_act(float* p, float v) { *p = v; }
__device__ __forceinline__ void store_act(unsigned short* p, float v) { *p = f32_to_bf16(v); }

// ---------------- padding / halo utilities ----------------
__global__ __launch_bounds__(256)
void pad_input_p(const float* __restrict__ x, float* __restrict__ xp,
                 int BC, int D, int PRX)
{
    int PD = D + 2;
    long total = (long)BC * PD * PD * PRX;
    long idx = (long)blockIdx.x * blockDim.x + threadIdx.x;
    if (idx >= total) return;
    int px = (int)(idx % PRX); long t = idx / PRX;
    int py = (int)(t % PD); t /= PD;
    int pz = (int)(t % PD); int c = (int)(t / PD);
    int ix = px - 1, iy = py - 1, iz = pz - 1;
    float v = 0.0f;
    if ((unsigned)ix < (unsigned)D && (unsigned)iy < (unsigned)D && (unsigned)iz < (unsigned)D)
        v = x[(((long)c * D + iz) * D + iy) * D + ix];
    xp[idx] = v;
}

__global__ __launch_bounds__(256)
void zero_halo_p(float* __restrict__ p, int C, int PD, int PRX)
{
    long total = (long)C * PD * PD * PRX;
    long idx = (long)blockIdx.x * blockDim.x + threadIdx.x;
    if (idx >= total) return;
    int px = (int)(idx % PRX); long t = idx / PRX;
    int py = (int)(t % PD); t /= PD;
    int pz = (int)(t % PD);
    if (px == 0 || px >= PD - 1 || py == 0 || py == PD - 1 || pz == 0 || pz == PD - 1)
        p[idx] = 0.0f;
}

template <typename T>
__global__ __launch_bounds__(256) void zero_halo_t(T* __restrict__ p, int C, int PD)
{
    long total = (long)C * PD * PD * PD;
    long idx = (long)blockIdx.x * blockDim.x + threadIdx.x;
    if (idx >= total) return;
    int px = (int)(idx % PD); long t = idx / PD;
    int py = (int)(t % PD); t /= PD;
    int pz = (int)(t % PD);
    if (px == 0 || px == PD - 1 || py == 0 || py == PD - 1 || pz == 0 || pz == PD - 1)
        p[idx] = (T)0;
}

// ---------------- vector row load (alignment guaranteed by pitch) ----------
template <int S>
__device__ __forceinline__ void load_row(const float* __restrict__ p, float* v) {
    if constexpr (S == 6) {
        *(float4*)v = *(const float4*)p;
        *(float2*)(v + 4) = *(const float2*)(p + 4);
    } else if constexpr (S == 10) {
        *(float4*)v = *(const float4*)p;
        *(float4*)(v + 4) = *(const float4*)(p + 4);
        *(float2*)(v + 8) = *(const float2*)(p + 8);
    }
}

// ---------------------------------------------------------------------------
// Strided conv k=4 s=2 p=1 (+ReLU), (TZ,TY,TX) spatial tile x TCO channels
// per thread. co-group wave-uniform -> weights are s_loads; each staged
// plane value feeds TCO x (matched taps) FMAs.
// ---------------------------------------------------------------------------
template <int TZ, int TY, int TX, int TCO>
__global__ __launch_bounds__(256)
void conv_s2_tile_co(const float* __restrict__ xp, const float* __restrict__ wgt,
                     const float* __restrict__ bias, float* __restrict__ y,
                     int B, int Cin, int Cout, int Dout, int PD, int PRX,
                     int chunks, int OPD, int OPRX, int po)
{
    constexpr int SZ = 2 * TZ + 2, SY = 2 * TY + 2, SX = 2 * TX + 2;
    const int NTX = Dout / TX, NTY = Dout / TY, NTZ = Dout / TZ;
    const int NT = NTX * NTY * NTZ;
    const int NCOG = Cout / TCO;
    int bx = blockIdx.x;
    const int chunk = bx % chunks; bx /= chunks;
    const int cog = bx % NCOG;                // wave-uniform
    const int b  = bx / NCOG;
    const int co0 = cog * TCO;
    const int tile = chunk * 256 + (int)threadIdx.x;
    if (tile >= NT) return;
    const int tx = tile % NTX, ty = (tile / NTX) % NTY, tz = tile / (NTX * NTY);
    const int ibz = 2 * TZ * tz, iby = 2 * TY * ty, ibx = 2 * TX * tx;
    const long chs = (long)PD * PD * PRX;
    const float* xb = xp + (long)b * Cin * chs + ((long)ibz * PD + iby) * PRX + ibx;

    float acc[TCO][TZ][TY][TX];
    #pragma unroll
    for (int c = 0; c < TCO; ++c) {
        const float bv = bias[co0 + c];
        #pragma unroll
        for (int a = 0; a < TZ; ++a)
            #pragma unroll
            for (int e = 0; e < TY; ++e)
                #pragma unroll
                for (int d = 0; d < TX; ++d) acc[c][a][e][d] = bv;
    }

    for (int ci = 0; ci < Cin; ++ci) {
        const float* xc = xb + ci * chs;
        #pragma unroll
        for (int jz = 0; jz < SZ; ++jz) {
            float plane[SY][SX];
            #pragma unroll
            for (int jy = 0; jy < SY; ++jy)
                load_row<SX>(xc + ((long)jz * PD + jy) * PRX, plane[jy]);
            #pragma unroll
            for (int c = 0; c < TCO; ++c) {
                const float* wr = wgt + ((long)(co0 + c) * Cin + ci) * 64;  // s_load
                #pragma unroll
                for (int oz = 0; oz < TZ; ++oz) {
                    const int kz = jz - 2 * oz;
                    if (kz < 0 || kz > 3) continue;
                    #pragma unroll
                    for (int jy = 0; jy < SY; ++jy) {
                        #pragma unroll
                        for (int oy = 0; oy < TY; ++oy) {
                            const int ky = jy - 2 * oy;
                            if (ky < 0 || ky > 3) continue;
                            #pragma unroll
                            for (int jx = 0; jx < SX; ++jx) {
                                #pragma unroll
                                for (int ox = 0; ox < TX; ++ox) {
                                    const int kx = jx - 2 * ox;
                                    if (kx < 0 || kx > 3) continue;
                                    acc[c][oz][oy][ox] = fmaf(plane[jy][jx],
                                                              wr[(kz * 4 + ky) * 4 + kx],
                                                              acc[c][oz][oy][ox]);
                                }
                            }
                        }
                    }
                }
            }
        }
    }

    #pragma unroll
    for (int c = 0; c < TCO; ++c) {
        float* yb = y + (long)(b * Cout + co0 + c) * OPD * OPD * OPRX;
        #pragma unroll
        for (int oz = 0; oz < TZ; ++oz)
            #pragma unroll
            for (int oy = 0; oy < TY; ++oy)
                #pragma unroll
                for (int ox = 0; ox < TX; ++ox) {
                    int opz = TZ * tz + oz + po, opy = TY * ty + oy + po,
                        opx = TX * tx + ox + po;
                    yb[((long)opz * OPD + opy) * OPRX + opx] =
                        fmaxf(acc[c][oz][oy][ox], 0.0f);
                }
    }
}

// ---------------- 1x1 conv ----------------
__global__ __launch_bounds__(128)
void conv1x1_b(const float* __restrict__ x, const float* __restrict__ w,
               const float* __restrict__ bias, float* __restrict__ y)
{
    const int co = blockIdx.x & 255, b = blockIdx.x >> 8;
    const int s4 = (int)threadIdx.x * 4;
    const float* xb = x + (long)b * 256 * 512 + s4;
    const float* wr = w + (long)co * 256;      // uniform -> s_load
    float bv = bias[co];
    float4 acc = {bv, bv, bv, bv};
    for (int ci = 0; ci < 256; ++ci) {
        float wv = wr[ci];
        float4 xv = *(const float4*)(xb + (long)ci * 512);
        acc.x = fmaf(xv.x, wv, acc.x); acc.y = fmaf(xv.y, wv, acc.y);
        acc.z = fmaf(xv.z, wv, acc.z); acc.w = fmaf(xv.w, wv, acc.w);
    }
    *(float4*)(y + (long)(b * 256 + co) * 512 + s4) = acc;
}

// ---------------- VQ (fp32 exact; same summation order as R2-R4) ------------
__global__ void codenorm_kernel(const float* __restrict__ cb, float* __restrict__ norms)
{
    int k = blockIdx.x;
    int lane = threadIdx.x;
    float s = 0.0f;
    const float* row = cb + (long)k * 256;
    for (int d = lane; d < 256; d += 64) { float v = row[d]; s = fmaf(v, v, s); }
    for (int off = 32; off > 0; off >>= 1) s += __shfl_down(s, off);
    if (lane == 0) norms[k] = s;
}

__global__ __launch_bounds__(256)
void vq_kernel(const float* __restrict__ lat, const float* __restrict__ cb,
               const float* __restrict__ norms, unsigned short* __restrict__ q,
               float* __restrict__ idx_out)
{
    __shared__ __align__(16) float row[256];
    __shared__ float s_best[256];
    __shared__ int   s_bidx[256];
    int r = blockIdx.x;
    int t = threadIdx.x;
    row[t] = lat[(long)r * 256 + t];
    __syncthreads();

    const float4* rowv = (const float4*)row;
    float latn = 0.0f;
    #pragma unroll 4
    for (int d = 0; d < 64; ++d) {
        float4 rv = rowv[d];
        latn = fmaf(rv.x, rv.x, latn); latn = fmaf(rv.y, rv.y, latn);
        latn = fmaf(rv.z, rv.z, latn); latn = fmaf(rv.w, rv.w, latn);
    }

    float best = FLT_MAX;
    int bidx = 0x7fffffff;
    for (int j = 0; j < 4; ++j) {
        int k = t + 256 * j;
        const float4* cr = (const float4*)(cb + (long)k * 256);
        float dot = 0.0f;
        #pragma unroll 4
        for (int d = 0; d < 64; ++d) {
            float4 c = cr[d]; float4 rv = rowv[d];
            dot = fmaf(rv.x, c.x, dot); dot = fmaf(rv.y, c.y, dot);
            dot = fmaf(rv.z, c.z, dot); dot = fmaf(rv.w, c.w, dot);
        }
        float sc = latn - 2.0f * dot + norms[k];
        if (sc < best || (sc == best && k < bidx)) { best = sc; bidx = k; }
    }
    s_best[t] = best; s_bidx[t] = bidx;
    __syncthreads();
    for (int off = 128; off > 0; off >>= 1) {
        if (t < off) {
            float o = s_best[t + off]; int oi = s_bidx[t + off];
            if (o < s_best[t] || (o == s_best[t] && oi < s_bidx[t])) {
                s_best[t] = o; s_bidx[t] = oi;
            }
        }
        __syncthreads();
    }
    int bk = s_bidx[0];
    int b = r >> 9, n = r & 511;
    int zz = n >> 6, yy = (n >> 3) & 7, xx = n & 7;
    q[(long)(b * 256 + t) * 1000 + ((long)(zz + 1) * 10 + (yy + 1)) * 10 + (xx + 1)]
        = f32_to_bf16(cb[(long)bk * 256 + t]);
    if (t == 0) idx_out[r] = (float)bk;
}

// ---------------- decoder: MFMA implicit-GEMM ConvTranspose ----------------
__global__ __launch_bounds__(256)
void prep_convt_w(const float* __restrict__ w, short* __restrict__ Ap,
                  int Cin, int Cout)
{
    const int K = Cin * 8;
    long total = 8L * Cout * K;
    long idx = (long)blockIdx.x * blockDim.x + threadIdx.x;
    if (idx >= total) return;
    int k = (int)(idx % K);
    int co = (int)((idx / K) % Cout);
    int p = (int)(idx / ((long)K * Cout));
    int ci = k >> 3, a = k & 7;
    int az = (a >> 2) & 1, ay = (a >> 1) & 1, ax = a & 1;
    int pz = p >> 2, py = (p >> 1) & 1, px = p & 1;
    int kd = (1 - pz) + 2 * az, kh = (1 - py) + 2 * ay, kw = (1 - px) + 2 * ax;
    float v = w[((long)ci * Cout + co) * 64 + kd * 16 + kh * 4 + kw];
    Ap[idx] = (short)f32_to_bf16(v);
}

template <int DIN, int OPAD, typename OutT>
__global__ __launch_bounds__(256)
void convt_mfma(const unsigned short* __restrict__ Xp, const short* __restrict__ Ap,
                const float* __restrict__ bias, OutT* __restrict__ Y,
                int Cin, int Cout)
{
    constexpr int PD = DIN + 2;
    constexpr int PD3 = PD * PD * PD;
    constexpr int T = DIN >> 2;
    constexpr int NT = T * T * T;
    constexpr int OPD = 2 * DIN + 2 * OPAD;
    const int K = Cin * 8;
    const int MG = Cout >> 6;

    int bx = blockIdx.x;
    const int mg = bx % MG; bx /= MG;
    const int nt = bx % NT; bx /= NT;
    const int p = bx;
    const int pz = p >> 2, py = (p >> 1) & 1, px = p & 1;

    const int lane = threadIdx.x & 63, wave = threadIdx.x >> 6;
    const int n16 = lane & 15, quad = lane >> 4;

    const int tx = nt % T, ty = (nt / T) % T, tz = nt / (T * T);
    const int mz = tz * 4 + wave, my = ty * 4 + (n16 >> 2), mx = tx * 4 + (n16 & 3);
    const int sp = ((mz + pz) * PD + (my + py)) * PD + (mx + px);

    const unsigned short* xq = Xp + (long)quad * PD3 + sp;

    const int cobase = mg * 64;
    const short* ap0 = Ap + ((long)p * Cout + cobase + n16) * K + quad * 8;

    f32x4 acc[4];
    #pragma unroll
    for (int cb = 0; cb < 4; ++cb) {
        const float* bp = bias + cobase + cb * 16 + quad * 4;
        acc[cb][0] = bp[0]; acc[cb][1] = bp[1]; acc[cb][2] = bp[2]; acc[cb][3] = bp[3];
    }

    const int nsteps = K >> 5;
    for (int s = 0; s < nsteps; ++s) {
        bf16x8 bf;
        bf[0] = (short)xq[(PD + 1) * PD + 1];
        bf[1] = (short)xq[(PD + 1) * PD];
        bf[2] = (short)xq[PD * PD + 1];
        bf[3] = (short)xq[PD * PD];
        bf[4] = (short)xq[PD + 1];
        bf[5] = (short)xq[PD];
        bf[6] = (short)xq[1];
        bf[7] = (short)xq[0];
        #pragma unroll
        for (int cb = 0; cb < 4; ++cb) {
            bf16x8 af = *(const bf16x8*)(ap0 + (long)cb * 16 * K + s * 32);
            acc[cb] = __builtin_amdgcn_mfma_f32_16x16x32_bf16(af, bf, acc[cb], 0, 0, 0);
        }
        xq += 4 * PD3;
    }

    const int opz = 2 * mz + pz + OPAD, opy = 2 * my + py + OPAD, opx = 2 * mx + px + OPAD;
    const long spo = ((long)opz * OPD + opy) * OPD + opx;
    #pragma unroll
    for (int cb = 0; cb < 4; ++cb) {
        #pragma unroll
        for (int r = 0; r < 4; ++r) {
            int co = cobase + cb * 16 + quad * 4 + r;
            float v = fmaxf(acc[cb][r], 0.0f);
            store_act(Y + (long)co * OPD * OPD * OPD + spo, v);
        }
    }
}

// ---------------- dec4 as MFMA GEMM: M=16 (3 used), N=61^3, K=4096 ----------
__global__ __launch_bounds__(256)
void prep_dec4A(const float* __restrict__ w, short* __restrict__ Aw)
{
    int idx = blockIdx.x * 256 + (int)threadIdx.x;    // 0..65535
    int m = idx >> 12, k = idx & 4095;
    float v = (m < 3) ? w[m * 4096 + k] : 0.0f;
    Aw[idx] = (short)f32_to_bf16(v);
}

__global__ __launch_bounds__(256)
void conv_dec4_mfma(const float* __restrict__ d3, const short* __restrict__ Aw,
                    const float* __restrict__ bias, float* __restrict__ y)
{
    constexpr int D = 64, Dout = 61;
    const int oh = blockIdx.x % Dout, od = blockIdx.x / Dout;
    const int lane = (int)threadIdx.x & 63, wave = (int)threadIdx.x >> 6;
    const int n16 = lane & 15, quad = lane >> 4;
    const int ow = wave * 16 + n16;

    f32x4 acc;
    #pragma unroll
    for (int r = 0; r < 4; ++r) {
        int co = quad * 4 + r;
        acc[r] = (co < 3) ? bias[co] : 0.0f;
    }

    const short* ap = Aw + (long)n16 * 4096 + quad * 8;   // m = lane&15
    const int kd0 = quad >> 1;
    const int kh0 = (quad & 1) * 2;
    const float* base0 = d3 + ((long)(od + kd0) * D + (oh + kh0)) * D + ow;

    #pragma unroll 4
    for (int s = 0; s < 128; ++s) {
        const int ci = s >> 1;
        const float* base = base0 + ((long)ci * D + (s & 1) * 2) * D * D;
        f32x4u r0 = *(const f32x4u*)base;
        f32x4u r1 = *(const f32x4u*)(base + D);
        bf16x8 bf;
        bf[0] = (short)(__float_as_uint(r0.x) >> 16);
        bf[1] = (short)(__float_as_uint(r0.y) >> 16);
        bf[2] = (short)(__float_as_uint(r0.z) >> 16);
        bf[3] = (short)(__float_as_uint(r0.w) >> 16);
        bf[4] = (short)(__float_as_uint(r1.x) >> 16);
        bf[5] = (short)(__float_as_uint(r1.y) >> 16);
        bf[6] = (short)(__float_as_uint(r1.z) >> 16);
        bf[7] = (short)(__float_as_uint(r1.w) >> 16);
        bf16x8 af = *(const bf16x8*)(ap + s * 32);
        acc = __builtin_amdgcn_mfma_f32_16x16x32_bf16(af, bf, acc, 0, 0, 0);
    }

    if (ow < Dout && quad == 0) {
        #pragma unroll
        for (int r = 0; r < 3; ++r)
            y[((long)(r * Dout + od) * Dout + oh) * Dout + ow] = tanhf(acc[r]);
    }
}

extern "C" void kernel_launch(void* const* d_in, const int* in_sizes, int n_in,
                              void* d_out, int out_size, void* d_ws, size_t ws_size,
                              hipStream_t stream)
{
    const float* x        = (const float*)d_in[0];
    const float* enc_w1   = (const float*)d_in[1];
    const float* enc_b1   = (const float*)d_in[2];
    const float* enc_w2   = (const float*)d_in[3];
    const float* enc_b2   = (const float*)d_in[4];
    const float* enc_w3   = (const float*)d_in[5];
    const float* enc_b3   = (const float*)d_in[6];
    const float* enc_w4   = (const float*)d_in[7];
    const float* enc_b4   = (const float*)d_in[8];
    const float* codebook = (const float*)d_in[9];
    const float* dec_w1   = (const float*)d_in[10];
    const float* dec_b1   = (const float*)d_in[11];
    const float* dec_w2   = (const float*)d_in[12];
    const float* dec_b2   = (const float*)d_in[13];
    const float* dec_w3   = (const float*)d_in[14];
    const float* dec_b3   = (const float*)d_in[15];
    const float* dec_w4   = (const float*)d_in[16];
    const float* dec_b4   = (const float*)d_in[17];

    float* out = (float*)d_out;
    float* idx_out = out + 2L * 3 * 61 * 61 * 61;

    // ---- workspace (byte offsets; persistent | overlapped arena) ----
    char* wsb = (char*)d_ws;
    float*          cn  = (float*)wsb;                       //     4,096 B
    unsigned short* qp  = (unsigned short*)(wsb + 4096);     // 1,024,000 B
    short*          Ap1 = (short*)(wsb + 1028096);           // 8,388,608 B
    short*          Ap2 = (short*)(wsb + 9416704);           // 4,194,304 B
    short*          Ap3 = (short*)(wsb + 13611008);          // 1,048,576 B
    short*          Aw4 = (short*)(wsb + 14659584);          //   131,072 B
    char* arena = wsb + 14790656;
    // encoder phase (fp32, x-pitched padded):
    float* xp  = (float*)arena;                  // (2,3,66,66,68)  = 1,777,248 f
    float* h1p = (float*)arena + 1777248;        // (2,64,34,34,36) = 5,326,848 f
    float* h2p = (float*)arena + 7104096;        // (2,128,18,18,20)= 1,658,880 f
    float* h3  = (float*)arena + 8762976;        // (2,256,8^3)     =   262,144 f
    float* lat = (float*)arena + 9025120;        //                   262,144 f
    // decoder phase (after VQ; overlaps encoder buffers):
    unsigned short* d1 = (unsigned short*)arena;               // (256,18^3) bf16
    unsigned short* d2 = (unsigned short*)(arena + 2985984);   // (128,34^3) bf16
    float*          d3 = (float*)(arena + 13047808);           // (64,64^3) fp32
    // arena peak 80.2 MB; total ~94.9 MB (< 112 MB proven in R0)

    dim3 blk(256);
    auto nblk = [](long n) { return dim3((unsigned)((n + 255) / 256)); };

    // ---- decoder weight pre-gather ----
    prep_convt_w<<<nblk(8L * 256 * 2048), blk, 0, stream>>>(dec_w1, Ap1, 256, 256);
    prep_convt_w<<<nblk(8L * 128 * 2048), blk, 0, stream>>>(dec_w2, Ap2, 256, 128);
    prep_convt_w<<<nblk(8L * 64 * 1024), blk, 0, stream>>>(dec_w3, Ap3, 128, 64);
    prep_dec4A<<<dim3(256), blk, 0, stream>>>(dec_w4, Aw4);

    // ---- encoder (fp32, pitched, co-blocked) ----
    pad_input_p<<<nblk(6L * 66 * 66 * 68), blk, 0, stream>>>(x, xp, 6, 64, 68);
    zero_halo_p<<<nblk(128L * 34 * 34 * 36), blk, 0, stream>>>(h1p, 128, 34, 36);
    // enc1: Cin=3 Cout=64 Dout=32, tile(2,2,4) TCO=2: NT=2048, chunks=8, grid=2*32*8
    conv_s2_tile_co<2, 2, 4, 2><<<dim3(2 * 32 * 8), blk, 0, stream>>>(
        xp, enc_w1, enc_b1, h1p, 2, 3, 64, 32, 66, 68, 8, 34, 36, 1);
    zero_halo_p<<<nblk(256L * 18 * 18 * 20), blk, 0, stream>>>(h2p, 256, 18, 20);
    // enc2: Cin=64 Cout=128 Dout=16, tile(1,2,2) TCO=4: NT=1024, chunks=4, grid=2*32*4
    conv_s2_tile_co<1, 2, 2, 4><<<dim3(2 * 32 * 4), blk, 0, stream>>>(
        h1p, enc_w2, enc_b2, h2p, 2, 64, 128, 16, 34, 36, 4, 18, 20, 1);
    // enc3: Cin=128 Cout=256 Dout=8, tile(1,1,2) TCO=4: NT=256, chunks=1, grid=2*64
    conv_s2_tile_co<1, 1, 2, 4><<<dim3(2 * 64), blk, 0, stream>>>(
        h2p, enc_w3, enc_b3, h3, 2, 128, 256, 8, 18, 20, 1, 8, 8, 0);
    conv1x1_b<<<dim3(512), dim3(128), 0, stream>>>(h3, enc_w4, enc_b4, lat);

    // ---- VQ (fp32 exact) ----
    codenorm_kernel<<<dim3(1024), dim3(64), 0, stream>>>(codebook, cn);
    zero_halo_t<unsigned short><<<nblk(512L * 10 * 10 * 10), blk, 0, stream>>>(qp, 512, 10);
    vq_kernel<<<dim3(1024), blk, 0, stream>>>(lat, codebook, cn, qp, idx_out);

    // ---- decoder halos ----
    zero_halo_t<unsigned short><<<nblk(256L * 18 * 18 * 18), blk, 0, stream>>>(d1, 256, 18);
    zero_halo_t<unsigned short><<<nblk(128L * 34 * 34 * 34), blk, 0, stream>>>(d2, 128, 34);

    // ---- decoder (MFMA) per batch ----
    for (int b = 0; b < 2; ++b) {
        const unsigned short* qb = qp + (long)b * 256 * 1000;
        float* outb = out + (long)b * 3 * 226981;
        convt_mfma<8, 1, unsigned short><<<dim3(8 * 8 * 4), blk, 0, stream>>>(
            qb, Ap1, dec_b1, d1, 256, 256);
        convt_mfma<16, 1, unsigned short><<<dim3(8 * 64 * 2), blk, 0, stream>>>(
            d1, Ap2, dec_b2, d2, 256, 128);
        convt_mfma<32, 0, float><<<dim3(8 * 512), blk, 0, stream>>>(
            d2, Ap3, dec_b3, d3, 128, 64);
        conv_dec4_mfma<<<dim3(61 * 61), blk, 0, stream>>>(d3, Aw4, dec_b4, outb);
    }
}

// Round 7
// 2909.727 us; speedup vs baseline: 1.1471x; 1.1471x over previous
//
#include <hip/hip_runtime.h>
#include <cfloat>
#include <cmath>

// ---------------------------------------------------------------------------
// Round 6: revert R6's occupancy-killing co-blocking. enc1/enc3 = R5 configs
// (grid >= 512, latency-hiding proven). enc2 rebuilt: tile(1,1,2) x TCO=2 with
// full-cube register staging per ci (one vmcnt batch per 256 FMAs), grid kept
// at 1024 blocks. Latent summation order unchanged => VQ indices identical.
// Decoder MFMA path unchanged from R4/R5.
// ---------------------------------------------------------------------------

using f32x4  = __attribute__((ext_vector_type(4))) float;
using bf16x8 = __attribute__((ext_vector_type(8))) short;
typedef float f32x4u __attribute__((ext_vector_type(4), aligned(4)));  // 4B-aligned vec load

__device__ __forceinline__ unsigned short f32_to_bf16(float f) {
    unsigned int u = __float_as_uint(f);
    u += 0x7fffu + ((u >> 16) & 1u);          // round-to-nearest-even
    return (unsigned short)(u >> 16);
}
__device__ __forceinline__ void store_act(float* p, float v) { *p = v; }
__device__ __forceinline__ void store_act(unsigned short* p, float v) { *p = f32_to_bf16(v); }

// ---------------- padding / halo utilities ----------------
__global__ __launch_bounds__(256)
void pad_input_p(const float* __restrict__ x, float* __restrict__ xp,
                 int BC, int D, int PRX)
{
    int PD = D + 2;
    long total = (long)BC * PD * PD * PRX;
    long idx = (long)blockIdx.x * blockDim.x + threadIdx.x;
    if (idx >= total) return;
    int px = (int)(idx % PRX); long t = idx / PRX;
    int py = (int)(t % PD); t /= PD;
    int pz = (int)(t % PD); int c = (int)(t / PD);
    int ix = px - 1, iy = py - 1, iz = pz - 1;
    float v = 0.0f;
    if ((unsigned)ix < (unsigned)D && (unsigned)iy < (unsigned)D && (unsigned)iz < (unsigned)D)
        v = x[(((long)c * D + iz) * D + iy) * D + ix];
    xp[idx] = v;
}

__global__ __launch_bounds__(256)
void zero_halo_p(float* __restrict__ p, int C, int PD, int PRX)
{
    long total = (long)C * PD * PD * PRX;
    long idx = (long)blockIdx.x * blockDim.x + threadIdx.x;
    if (idx >= total) return;
    int px = (int)(idx % PRX); long t = idx / PRX;
    int py = (int)(t % PD); t /= PD;
    int pz = (int)(t % PD);
    if (px == 0 || px >= PD - 1 || py == 0 || py == PD - 1 || pz == 0 || pz == PD - 1)
        p[idx] = 0.0f;
}

template <typename T>
__global__ __launch_bounds__(256) void zero_halo_t(T* __restrict__ p, int C, int PD)
{
    long total = (long)C * PD * PD * PD;
    long idx = (long)blockIdx.x * blockDim.x + threadIdx.x;
    if (idx >= total) return;
    int px = (int)(idx % PD); long t = idx / PD;
    int py = (int)(t % PD); t /= PD;
    int pz = (int)(t % PD);
    if (px == 0 || px == PD - 1 || py == 0 || py == PD - 1 || pz == 0 || pz == PD - 1)
        p[idx] = (T)0;
}

// ---------------- vector row load (alignment guaranteed by pitch) ----------
template <int S>
__device__ __forceinline__ void load_row(const float* __restrict__ p, float* v) {
    if constexpr (S == 6) {
        *(float4*)v = *(const float4*)p;
        *(float2*)(v + 4) = *(const float2*)(p + 4);
    } else if constexpr (S == 10) {
        *(float4*)v = *(const float4*)p;
        *(float4*)(v + 4) = *(const float4*)(p + 4);
        *(float2*)(v + 8) = *(const float2*)(p + 8);
    }
}

// ---------------------------------------------------------------------------
// Strided conv k=4 s=2 p=1 (+ReLU), (TZ,TY,TX) output tile per thread (R5).
// ---------------------------------------------------------------------------
template <int TZ, int TY, int TX>
__global__ __launch_bounds__(256)
void conv_s2_tile(const float* __restrict__ xp, const float* __restrict__ wgt,
                  const float* __restrict__ bias, float* __restrict__ y,
                  int B, int Cin, int Cout, int Dout, int PD, int PRX,
                  int chunks, int OPD, int OPRX, int po)
{
    constexpr int SZ = 2 * TZ + 2, SY = 2 * TY + 2, SX = 2 * TX + 2;
    const int NTX = Dout / TX, NTY = Dout / TY, NTZ = Dout / TZ;
    const int NT = NTX * NTY * NTZ;
    int bx = blockIdx.x;
    const int chunk = bx % chunks; bx /= chunks;
    const int co = bx % Cout;                 // wave-uniform
    const int b  = bx / Cout;
    const int tile = chunk * 256 + (int)threadIdx.x;
    if (tile >= NT) return;
    const int tx = tile % NTX, ty = (tile / NTX) % NTY, tz = tile / (NTX * NTY);
    const int ibz = 2 * TZ * tz, iby = 2 * TY * ty, ibx = 2 * TX * tx;
    const long chs = (long)PD * PD * PRX;
    const float* xb = xp + (long)b * Cin * chs + ((long)ibz * PD + iby) * PRX + ibx;
    const float* wb = wgt + (long)co * Cin * 64;

    const float bv = bias[co];
    float acc[TZ][TY][TX];
    #pragma unroll
    for (int a = 0; a < TZ; ++a)
        #pragma unroll
        for (int c = 0; c < TY; ++c)
            #pragma unroll
            for (int d = 0; d < TX; ++d) acc[a][c][d] = bv;

    for (int ci = 0; ci < Cin; ++ci) {
        const float* wr = wb + ci * 64;        // uniform -> s_load
        const float* xc = xb + ci * chs;
        #pragma unroll
        for (int jz = 0; jz < SZ; ++jz) {
            float plane[SY][SX];
            #pragma unroll
            for (int jy = 0; jy < SY; ++jy)
                load_row<SX>(xc + ((long)jz * PD + jy) * PRX, plane[jy]);
            #pragma unroll
            for (int oz = 0; oz < TZ; ++oz) {
                const int kz = jz - 2 * oz;
                if (kz < 0 || kz > 3) continue;
                #pragma unroll
                for (int jy = 0; jy < SY; ++jy) {
                    #pragma unroll
                    for (int oy = 0; oy < TY; ++oy) {
                        const int ky = jy - 2 * oy;
                        if (ky < 0 || ky > 3) continue;
                        #pragma unroll
                        for (int jx = 0; jx < SX; ++jx) {
                            #pragma unroll
                            for (int ox = 0; ox < TX; ++ox) {
                                const int kx = jx - 2 * ox;
                                if (kx < 0 || kx > 3) continue;
                                acc[oz][oy][ox] = fmaf(plane[jy][jx],
                                                       wr[(kz * 4 + ky) * 4 + kx],
                                                       acc[oz][oy][ox]);
                            }
                        }
                    }
                }
            }
        }
    }

    float* yb = y + (long)(b * Cout + co) * OPD * OPD * OPRX;
    #pragma unroll
    for (int oz = 0; oz < TZ; ++oz)
        #pragma unroll
        for (int oy = 0; oy < TY; ++oy)
            #pragma unroll
            for (int ox = 0; ox < TX; ++ox) {
                int opz = TZ * tz + oz + po, opy = TY * ty + oy + po, opx = TX * tx + ox + po;
                yb[((long)opz * OPD + opy) * OPRX + opx] = fmaxf(acc[oz][oy][ox], 0.0f);
            }
}

// ---------------------------------------------------------------------------
// enc2 specialized: Cin=64 Cout=128 Dout=16, tile(1,1,2) x TCO=2, full-cube
// register staging per ci. grid = 2*64*8 = 1024 blocks (latency-hiding kept).
// Per-output summation order (ci,jz,jy,jx ascending) identical to R5.
// ---------------------------------------------------------------------------
__global__ __launch_bounds__(256, 3)
void conv_s2_stage2(const float* __restrict__ xp, const float* __restrict__ wgt,
                    const float* __restrict__ bias, float* __restrict__ y)
{
    constexpr int Cin = 64, Cout = 128, PD = 34, PRX = 36, OPD = 18, OPRX = 20;
    constexpr int NTX = 8, NTY = 16, chunks = 8, NCOG = 64;
    int bx = blockIdx.x;
    const int chunk = bx % chunks; bx /= chunks;
    const int cog = bx % NCOG;                 // wave-uniform
    const int b = bx / NCOG;
    const int co0 = cog * 2;
    const int tile = chunk * 256 + (int)threadIdx.x;   // < 2048 always
    const int tx = tile % NTX, ty = (tile / NTX) % NTY, tz = tile / (NTX * NTY);
    const int ibz = 2 * tz, iby = 2 * ty, ibx = 4 * tx;   // ibx 16B-aligned
    const long chs = (long)PD * PD * PRX;
    const float* xb = xp + (long)b * Cin * chs + ((long)ibz * PD + iby) * PRX + ibx;

    const float bv0 = bias[co0], bv1 = bias[co0 + 1];
    float acc[2][2];                      // [co][ox]
    acc[0][0] = bv0; acc[0][1] = bv0;
    acc[1][0] = bv1; acc[1][1] = bv1;

    const float* w0 = wgt + (long)co0 * Cin * 64;   // uniform -> s_load
    const float* w1 = w0 + Cin * 64;

    for (int ci = 0; ci < Cin; ++ci) {
        const float* xc = xb + ci * chs;
        float cube[4][4][6];
        #pragma unroll
        for (int jz = 0; jz < 4; ++jz)
            #pragma unroll
            for (int jy = 0; jy < 4; ++jy) {
                const float* rp = xc + ((long)jz * PD + jy) * PRX;
                *(float4*)cube[jz][jy] = *(const float4*)rp;
                *(float2*)(cube[jz][jy] + 4) = *(const float2*)(rp + 4);
            }
        const float* wr0 = w0 + ci * 64;
        const float* wr1 = w1 + ci * 64;
        #pragma unroll
        for (int jz = 0; jz < 4; ++jz)
            #pragma unroll
            for (int jy = 0; jy < 4; ++jy) {
                const int kb = (jz * 4 + jy) * 4;
                #pragma unroll
                for (int jx = 0; jx < 6; ++jx) {
                    const float xv = cube[jz][jy][jx];
                    if (jx < 4) {                      // ox=0: kx=jx
                        acc[0][0] = fmaf(xv, wr0[kb + jx], acc[0][0]);
                        acc[1][0] = fmaf(xv, wr1[kb + jx], acc[1][0]);
                    }
                    if (jx >= 2) {                     // ox=1: kx=jx-2
                        acc[0][1] = fmaf(xv, wr0[kb + jx - 2], acc[0][1]);
                        acc[1][1] = fmaf(xv, wr1[kb + jx - 2], acc[1][1]);
                    }
                }
            }
    }

    const int opz = tz + 1, opy = ty + 1;
    #pragma unroll
    for (int c = 0; c < 2; ++c) {
        float* yb = y + (long)(b * Cout + co0 + c) * OPD * OPD * OPRX;
        #pragma unroll
        for (int ox = 0; ox < 2; ++ox)
            yb[((long)opz * OPD + opy) * OPRX + 2 * tx + ox + 1] =
                fmaxf(acc[c][ox], 0.0f);
    }
}

// ---------------- 1x1 conv ----------------
__global__ __launch_bounds__(128)
void conv1x1_b(const float* __restrict__ x, const float* __restrict__ w,
               const float* __restrict__ bias, float* __restrict__ y)
{
    const int co = blockIdx.x & 255, b = blockIdx.x >> 8;
    const int s4 = (int)threadIdx.x * 4;
    const float* xb = x + (long)b * 256 * 512 + s4;
    const float* wr = w + (long)co * 256;      // uniform -> s_load
    float bv = bias[co];
    float4 acc = {bv, bv, bv, bv};
    for (int ci = 0; ci < 256; ++ci) {
        float wv = wr[ci];
        float4 xv = *(const float4*)(xb + (long)ci * 512);
        acc.x = fmaf(xv.x, wv, acc.x); acc.y = fmaf(xv.y, wv, acc.y);
        acc.z = fmaf(xv.z, wv, acc.z); acc.w = fmaf(xv.w, wv, acc.w);
    }
    *(float4*)(y + (long)(b * 256 + co) * 512 + s4) = acc;
}

// ---------------- VQ (fp32 exact; same summation order as R2-R5) ------------
__global__ void codenorm_kernel(const float* __restrict__ cb, float* __restrict__ norms)
{
    int k = blockIdx.x;
    int lane = threadIdx.x;
    float s = 0.0f;
    const float* row = cb + (long)k * 256;
    for (int d = lane; d < 256; d += 64) { float v = row[d]; s = fmaf(v, v, s); }
    for (int off = 32; off > 0; off >>= 1) s += __shfl_down(s, off);
    if (lane == 0) norms[k] = s;
}

__global__ __launch_bounds__(256)
void vq_kernel(const float* __restrict__ lat, const float* __restrict__ cb,
               const float* __restrict__ norms, unsigned short* __restrict__ q,
               float* __restrict__ idx_out)
{
    __shared__ __align__(16) float row[256];
    __shared__ float s_best[256];
    __shared__ int   s_bidx[256];
    int r = blockIdx.x;
    int t = threadIdx.x;
    row[t] = lat[(long)r * 256 + t];
    __syncthreads();

    const float4* rowv = (const float4*)row;
    float latn = 0.0f;
    #pragma unroll 4
    for (int d = 0; d < 64; ++d) {
        float4 rv = rowv[d];
        latn = fmaf(rv.x, rv.x, latn); latn = fmaf(rv.y, rv.y, latn);
        latn = fmaf(rv.z, rv.z, latn); latn = fmaf(rv.w, rv.w, latn);
    }

    float best = FLT_MAX;
    int bidx = 0x7fffffff;
    for (int j = 0; j < 4; ++j) {
        int k = t + 256 * j;
        const float4* cr = (const float4*)(cb + (long)k * 256);
        float dot = 0.0f;
        #pragma unroll 4
        for (int d = 0; d < 64; ++d) {
            float4 c = cr[d]; float4 rv = rowv[d];
            dot = fmaf(rv.x, c.x, dot); dot = fmaf(rv.y, c.y, dot);
            dot = fmaf(rv.z, c.z, dot); dot = fmaf(rv.w, c.w, dot);
        }
        float sc = latn - 2.0f * dot + norms[k];
        if (sc < best || (sc == best && k < bidx)) { best = sc; bidx = k; }
    }
    s_best[t] = best; s_bidx[t] = bidx;
    __syncthreads();
    for (int off = 128; off > 0; off >>= 1) {
        if (t < off) {
            float o = s_best[t + off]; int oi = s_bidx[t + off];
            if (o < s_best[t] || (o == s_best[t] && oi < s_bidx[t])) {
                s_best[t] = o; s_bidx[t] = oi;
            }
        }
        __syncthreads();
    }
    int bk = s_bidx[0];
    int b = r >> 9, n = r & 511;
    int zz = n >> 6, yy = (n >> 3) & 7, xx = n & 7;
    q[(long)(b * 256 + t) * 1000 + ((long)(zz + 1) * 10 + (yy + 1)) * 10 + (xx + 1)]
        = f32_to_bf16(cb[(long)bk * 256 + t]);
    if (t == 0) idx_out[r] = (float)bk;
}

// ---------------- decoder: MFMA implicit-GEMM ConvTranspose ----------------
__global__ __launch_bounds__(256)
void prep_convt_w(const float* __restrict__ w, short* __restrict__ Ap,
                  int Cin, int Cout)
{
    const int K = Cin * 8;
    long total = 8L * Cout * K;
    long idx = (long)blockIdx.x * blockDim.x + threadIdx.x;
    if (idx >= total) return;
    int k = (int)(idx % K);
    int co = (int)((idx / K) % Cout);
    int p = (int)(idx / ((long)K * Cout));
    int ci = k >> 3, a = k & 7;
    int az = (a >> 2) & 1, ay = (a >> 1) & 1, ax = a & 1;
    int pz = p >> 2, py = (p >> 1) & 1, px = p & 1;
    int kd = (1 - pz) + 2 * az, kh = (1 - py) + 2 * ay, kw = (1 - px) + 2 * ax;
    float v = w[((long)ci * Cout + co) * 64 + kd * 16 + kh * 4 + kw];
    Ap[idx] = (short)f32_to_bf16(v);
}

template <int DIN, int OPAD, typename OutT>
__global__ __launch_bounds__(256)
void convt_mfma(const unsigned short* __restrict__ Xp, const short* __restrict__ Ap,
                const float* __restrict__ bias, OutT* __restrict__ Y,
                int Cin, int Cout)
{
    constexpr int PD = DIN + 2;
    constexpr int PD3 = PD * PD * PD;
    constexpr int T = DIN >> 2;
    constexpr int NT = T * T * T;
    constexpr int OPD = 2 * DIN + 2 * OPAD;
    const int K = Cin * 8;
    const int MG = Cout >> 6;

    int bx = blockIdx.x;
    const int mg = bx % MG; bx /= MG;
    const int nt = bx % NT; bx /= NT;
    const int p = bx;
    const int pz = p >> 2, py = (p >> 1) & 1, px = p & 1;

    const int lane = threadIdx.x & 63, wave = threadIdx.x >> 6;
    const int n16 = lane & 15, quad = lane >> 4;

    const int tx = nt % T, ty = (nt / T) % T, tz = nt / (T * T);
    const int mz = tz * 4 + wave, my = ty * 4 + (n16 >> 2), mx = tx * 4 + (n16 & 3);
    const int sp = ((mz + pz) * PD + (my + py)) * PD + (mx + px);

    const unsigned short* xq = Xp + (long)quad * PD3 + sp;

    const int cobase = mg * 64;
    const short* ap0 = Ap + ((long)p * Cout + cobase + n16) * K + quad * 8;

    f32x4 acc[4];
    #pragma unroll
    for (int cb = 0; cb < 4; ++cb) {
        const float* bp = bias + cobase + cb * 16 + quad * 4;
        acc[cb][0] = bp[0]; acc[cb][1] = bp[1]; acc[cb][2] = bp[2]; acc[cb][3] = bp[3];
    }

    const int nsteps = K >> 5;
    for (int s = 0; s < nsteps; ++s) {
        bf16x8 bf;
        bf[0] = (short)xq[(PD + 1) * PD + 1];
        bf[1] = (short)xq[(PD + 1) * PD];
        bf[2] = (short)xq[PD * PD + 1];
        bf[3] = (short)xq[PD * PD];
        bf[4] = (short)xq[PD + 1];
        bf[5] = (short)xq[PD];
        bf[6] = (short)xq[1];
        bf[7] = (short)xq[0];
        #pragma unroll
        for (int cb = 0; cb < 4; ++cb) {
            bf16x8 af = *(const bf16x8*)(ap0 + (long)cb * 16 * K + s * 32);
            acc[cb] = __builtin_amdgcn_mfma_f32_16x16x32_bf16(af, bf, acc[cb], 0, 0, 0);
        }
        xq += 4 * PD3;
    }

    const int opz = 2 * mz + pz + OPAD, opy = 2 * my + py + OPAD, opx = 2 * mx + px + OPAD;
    const long spo = ((long)opz * OPD + opy) * OPD + opx;
    #pragma unroll
    for (int cb = 0; cb < 4; ++cb) {
        #pragma unroll
        for (int r = 0; r < 4; ++r) {
            int co = cobase + cb * 16 + quad * 4 + r;
            float v = fmaxf(acc[cb][r], 0.0f);
            store_act(Y + (long)co * OPD * OPD * OPD + spo, v);
        }
    }
}

// ---------------- dec4 as MFMA GEMM: M=16 (3 used), N=61^3, K=4096 ----------
__global__ __launch_bounds__(256)
void prep_dec4A(const float* __restrict__ w, short* __restrict__ Aw)
{
    int idx = blockIdx.x * 256 + (int)threadIdx.x;    // 0..65535
    int m = idx >> 12, k = idx & 4095;
    float v = (m < 3) ? w[m * 4096 + k] : 0.0f;
    Aw[idx] = (short)f32_to_bf16(v);
}

__global__ __launch_bounds__(256)
void conv_dec4_mfma(const float* __restrict__ d3, const short* __restrict__ Aw,
                    const float* __restrict__ bias, float* __restrict__ y)
{
    constexpr int D = 64, Dout = 61;
    const int oh = blockIdx.x % Dout, od = blockIdx.x / Dout;
    const int lane = (int)threadIdx.x & 63, wave = (int)threadIdx.x >> 6;
    const int n16 = lane & 15, quad = lane >> 4;
    const int ow = wave * 16 + n16;

    f32x4 acc;
    #pragma unroll
    for (int r = 0; r < 4; ++r) {
        int co = quad * 4 + r;
        acc[r] = (co < 3) ? bias[co] : 0.0f;
    }

    const short* ap = Aw + (long)n16 * 4096 + quad * 8;   // m = lane&15
    const int kd0 = quad >> 1;
    const int kh0 = (quad & 1) * 2;
    const float* base0 = d3 + ((long)(od + kd0) * D + (oh + kh0)) * D + ow;

    #pragma unroll 4
    for (int s = 0; s < 128; ++s) {
        const int ci = s >> 1;
        const float* base = base0 + ((long)ci * D + (s & 1) * 2) * D * D;
        f32x4u r0 = *(const f32x4u*)base;
        f32x4u r1 = *(const f32x4u*)(base + D);
        bf16x8 bf;
        bf[0] = (short)(__float_as_uint(r0.x) >> 16);
        bf[1] = (short)(__float_as_uint(r0.y) >> 16);
        bf[2] = (short)(__float_as_uint(r0.z) >> 16);
        bf[3] = (short)(__float_as_uint(r0.w) >> 16);
        bf[4] = (short)(__float_as_uint(r1.x) >> 16);
        bf[5] = (short)(__float_as_uint(r1.y) >> 16);
        bf[6] = (short)(__float_as_uint(r1.z) >> 16);
        bf[7] = (short)(__float_as_uint(r1.w) >> 16);
        bf16x8 af = *(const bf16x8*)(ap + s * 32);
        acc = __builtin_amdgcn_mfma_f32_16x16x32_bf16(af, bf, acc, 0, 0, 0);
    }

    if (ow < Dout && quad == 0) {
        #pragma unroll
        for (int r = 0; r < 3; ++r)
            y[((long)(r * Dout + od) * Dout + oh) * Dout + ow] = tanhf(acc[r]);
    }
}

extern "C" void kernel_launch(void* const* d_in, const int* in_sizes, int n_in,
                              void* d_out, int out_size, void* d_ws, size_t ws_size,
                              hipStream_t stream)
{
    const float* x        = (const float*)d_in[0];
    const float* enc_w1   = (const float*)d_in[1];
    const float* enc_b1   = (const float*)d_in[2];
    const float* enc_w2   = (const float*)d_in[3];
    const float* enc_b2   = (const float*)d_in[4];
    const float* enc_w3   = (const float*)d_in[5];
    const float* enc_b3   = (const float*)d_in[6];
    const float* enc_w4   = (const float*)d_in[7];
    const float* enc_b4   = (const float*)d_in[8];
    const float* codebook = (const float*)d_in[9];
    const float* dec_w1   = (const float*)d_in[10];
    const float* dec_b1   = (const float*)d_in[11];
    const float* dec_w2   = (const float*)d_in[12];
    const float* dec_b2   = (const float*)d_in[13];
    const float* dec_w3   = (const float*)d_in[14];
    const float* dec_b3   = (const float*)d_in[15];
    const float* dec_w4   = (const float*)d_in[16];
    const float* dec_b4   = (const float*)d_in[17];

    float* out = (float*)d_out;
    float* idx_out = out + 2L * 3 * 61 * 61 * 61;

    // ---- workspace (byte offsets; persistent | overlapped arena) ----
    char* wsb = (char*)d_ws;
    float*          cn  = (float*)wsb;                       //     4,096 B
    unsigned short* qp  = (unsigned short*)(wsb + 4096);     // 1,024,000 B
    short*          Ap1 = (short*)(wsb + 1028096);           // 8,388,608 B
    short*          Ap2 = (short*)(wsb + 9416704);           // 4,194,304 B
    short*          Ap3 = (short*)(wsb + 13611008);          // 1,048,576 B
    short*          Aw4 = (short*)(wsb + 14659584);          //   131,072 B
    char* arena = wsb + 14790656;
    // encoder phase (fp32, x-pitched padded):
    float* xp  = (float*)arena;                  // (2,3,66,66,68)  = 1,777,248 f
    float* h1p = (float*)arena + 1777248;        // (2,64,34,34,36) = 5,326,848 f
    float* h2p = (float*)arena + 7104096;        // (2,128,18,18,20)= 1,658,880 f
    float* h3  = (float*)arena + 8762976;        // (2,256,8^3)     =   262,144 f
    float* lat = (float*)arena + 9025120;        //                   262,144 f
    // decoder phase (after VQ; overlaps encoder buffers):
    unsigned short* d1 = (unsigned short*)arena;               // (256,18^3) bf16
    unsigned short* d2 = (unsigned short*)(arena + 2985984);   // (128,34^3) bf16
    float*          d3 = (float*)(arena + 13047808);           // (64,64^3) fp32
    // arena peak 80.2 MB; total ~94.9 MB (< 112 MB proven in R0)

    dim3 blk(256);
    auto nblk = [](long n) { return dim3((unsigned)((n + 255) / 256)); };

    // ---- decoder weight pre-gather ----
    prep_convt_w<<<nblk(8L * 256 * 2048), blk, 0, stream>>>(dec_w1, Ap1, 256, 256);
    prep_convt_w<<<nblk(8L * 128 * 2048), blk, 0, stream>>>(dec_w2, Ap2, 256, 128);
    prep_convt_w<<<nblk(8L * 64 * 1024), blk, 0, stream>>>(dec_w3, Ap3, 128, 64);
    prep_dec4A<<<dim3(256), blk, 0, stream>>>(dec_w4, Aw4);

    // ---- encoder (fp32, pitched) ----
    pad_input_p<<<nblk(6L * 66 * 66 * 68), blk, 0, stream>>>(x, xp, 6, 64, 68);
    zero_halo_p<<<nblk(128L * 34 * 34 * 36), blk, 0, stream>>>(h1p, 128, 34, 36);
    // enc1 (R5 config): tile(2,2,4): NT=2048, chunks=8, grid=1024
    conv_s2_tile<2, 2, 4><<<dim3(2 * 64 * 8), blk, 0, stream>>>(
        xp, enc_w1, enc_b1, h1p, 2, 3, 64, 32, 66, 68, 8, 34, 36, 1);
    zero_halo_p<<<nblk(256L * 18 * 18 * 20), blk, 0, stream>>>(h2p, 256, 18, 20);
    // enc2 (new): staged tile(1,1,2) x TCO=2, grid = 2*64*8 = 1024
    conv_s2_stage2<<<dim3(2 * 64 * 8), blk, 0, stream>>>(h1p, enc_w2, enc_b2, h2p);
    // enc3 (R5 config): tile(1,1,2): NT=256, chunks=1, grid=512; tight out
    conv_s2_tile<1, 1, 2><<<dim3(2 * 256), blk, 0, stream>>>(
        h2p, enc_w3, enc_b3, h3, 2, 128, 256, 8, 18, 20, 1, 8, 8, 0);
    conv1x1_b<<<dim3(512), dim3(128), 0, stream>>>(h3, enc_w4, enc_b4, lat);

    // ---- VQ (fp32 exact) ----
    codenorm_kernel<<<dim3(1024), dim3(64), 0, stream>>>(codebook, cn);
    zero_halo_t<unsigned short><<<nblk(512L * 10 * 10 * 10), blk, 0, stream>>>(qp, 512, 10);
    vq_kernel<<<dim3(1024), blk, 0, stream>>>(lat, codebook, cn, qp, idx_out);

    // ---- decoder halos ----
    zero_halo_t<unsigned short><<<nblk(256L * 18 * 18 * 18), blk, 0, stream>>>(d1, 256, 18);
    zero_halo_t<unsigned short><<<nblk(128L * 34 * 34 * 34), blk, 0, stream>>>(d2, 128, 34);

    // ---- decoder (MFMA) per batch ----
    for (int b = 0; b < 2; ++b) {
        const unsigned short* qb = qp + (long)b * 256 * 1000;
        float* outb = out + (long)b * 3 * 226981;
        convt_mfma<8, 1, unsigned short><<<dim3(8 * 8 * 4), blk, 0, stream>>>(
            qb, Ap1, dec_b1, d1, 256, 256);
        convt_mfma<16, 1, unsigned short><<<dim3(8 * 64 * 2), blk, 0, stream>>>(
            d1, Ap2, dec_b2, d2, 256, 128);
        convt_mfma<32, 0, float><<<dim3(8 * 512), blk, 0, stream>>>(
            d2, Ap3, dec_b3, d3, 128, 64);
        conv_dec4_mfma<<<dim3(61 * 61), blk, 0, stream>>>(d3, Aw4, dec_b4, outb);
    }
}

// Round 8
// 2760.149 us; speedup vs baseline: 1.2093x; 1.0542x over previous
//
#include <hip/hip_runtime.h>
#include <cfloat>
#include <cmath>

// ---------------------------------------------------------------------------
// Round 7: revert enc2 to the R5-proven conv_s2_tile<1,2,2> shape and add
// Cin-split x2 ("split-K") to enc2 + enc3: doubles block count (latency
// hiding), halves per-thread work; combine kernel applies p0+p1 (+bias in p0)
// and ReLU. fp32-rounding-level change only => VQ indices safe.
// Decoder MFMA path unchanged from R4-R7.
// ---------------------------------------------------------------------------

using f32x4  = __attribute__((ext_vector_type(4))) float;
using bf16x8 = __attribute__((ext_vector_type(8))) short;
typedef float f32x4u __attribute__((ext_vector_type(4), aligned(4)));

__device__ __forceinline__ unsigned short f32_to_bf16(float f) {
    unsigned int u = __float_as_uint(f);
    u += 0x7fffu + ((u >> 16) & 1u);          // round-to-nearest-even
    return (unsigned short)(u >> 16);
}
__device__ __forceinline__ void store_act(float* p, float v) { *p = v; }
__device__ __forceinline__ void store_act(unsigned short* p, float v) { *p = f32_to_bf16(v); }

// ---------------- padding / halo utilities ----------------
__global__ __launch_bounds__(256)
void pad_input_p(const float* __restrict__ x, float* __restrict__ xp,
                 int BC, int D, int PRX)
{
    int PD = D + 2;
    long total = (long)BC * PD * PD * PRX;
    long idx = (long)blockIdx.x * blockDim.x + threadIdx.x;
    if (idx >= total) return;
    int px = (int)(idx % PRX); long t = idx / PRX;
    int py = (int)(t % PD); t /= PD;
    int pz = (int)(t % PD); int c = (int)(t / PD);
    int ix = px - 1, iy = py - 1, iz = pz - 1;
    float v = 0.0f;
    if ((unsigned)ix < (unsigned)D && (unsigned)iy < (unsigned)D && (unsigned)iz < (unsigned)D)
        v = x[(((long)c * D + iz) * D + iy) * D + ix];
    xp[idx] = v;
}

__global__ __launch_bounds__(256)
void zero_halo_p(float* __restrict__ p, int C, int PD, int PRX)
{
    long total = (long)C * PD * PD * PRX;
    long idx = (long)blockIdx.x * blockDim.x + threadIdx.x;
    if (idx >= total) return;
    int px = (int)(idx % PRX); long t = idx / PRX;
    int py = (int)(t % PD); t /= PD;
    int pz = (int)(t % PD);
    if (px == 0 || px >= PD - 1 || py == 0 || py == PD - 1 || pz == 0 || pz == PD - 1)
        p[idx] = 0.0f;
}

template <typename T>
__global__ __launch_bounds__(256) void zero_halo_t(T* __restrict__ p, int C, int PD)
{
    long total = (long)C * PD * PD * PD;
    long idx = (long)blockIdx.x * blockDim.x + threadIdx.x;
    if (idx >= total) return;
    int px = (int)(idx % PD); long t = idx / PD;
    int py = (int)(t % PD); t /= PD;
    int pz = (int)(t % PD);
    if (px == 0 || px == PD - 1 || py == 0 || py == PD - 1 || pz == 0 || pz == PD - 1)
        p[idx] = (T)0;
}

// ---------------- vector row load (alignment guaranteed by pitch) ----------
template <int S>
__device__ __forceinline__ void load_row(const float* __restrict__ p, float* v) {
    if constexpr (S == 6) {
        *(float4*)v = *(const float4*)p;
        *(float2*)(v + 4) = *(const float2*)(p + 4);
    } else if constexpr (S == 10) {
        *(float4*)v = *(const float4*)p;
        *(float4*)(v + 4) = *(const float4*)(p + 4);
        *(float2*)(v + 8) = *(const float2*)(p + 8);
    }
}

// ---------------------------------------------------------------------------
// Strided conv k=4 s=2 p=1, (TZ,TY,TX) output tile per thread, optional
// Cin-split: grid = B * Cout * nsplit * chunks; split s covers ci in
// [s*cspan, (s+1)*cspan); bias folded into split 0; relu only if relu!=0.
// Output written at y + s*sstride in (OPD,OPD,OPRX) layout at offset +po.
// ---------------------------------------------------------------------------
template <int TZ, int TY, int TX>
__global__ __launch_bounds__(256)
void conv_s2_tile(const float* __restrict__ xp, const float* __restrict__ wgt,
                  const float* __restrict__ bias, float* __restrict__ y,
                  int B, int CinTot, int cspan, int nsplit, int Cout, int Dout,
                  int PD, int PRX, int chunks, int OPD, int OPRX, int po,
                  int relu, long sstride)
{
    constexpr int SZ = 2 * TZ + 2, SY = 2 * TY + 2, SX = 2 * TX + 2;
    const int NTX = Dout / TX, NTY = Dout / TY, NTZ = Dout / TZ;
    const int NT = NTX * NTY * NTZ;
    int bx = blockIdx.x;
    const int chunk = bx % chunks; bx /= chunks;
    const int s = bx % nsplit; bx /= nsplit;
    const int co = bx % Cout;                 // wave-uniform
    const int b  = bx / Cout;
    const int ci0 = s * cspan;
    const int tile = chunk * 256 + (int)threadIdx.x;
    if (tile >= NT) return;
    const int tx = tile % NTX, ty = (tile / NTX) % NTY, tz = tile / (NTX * NTY);
    const int ibz = 2 * TZ * tz, iby = 2 * TY * ty, ibx = 2 * TX * tx;
    const long chs = (long)PD * PD * PRX;
    const float* xb = xp + ((long)b * CinTot + ci0) * chs + ((long)ibz * PD + iby) * PRX + ibx;
    const float* wb = wgt + ((long)co * CinTot + ci0) * 64;

    const float bv = (s == 0) ? bias[co] : 0.0f;
    float acc[TZ][TY][TX];
    #pragma unroll
    for (int a = 0; a < TZ; ++a)
        #pragma unroll
        for (int c = 0; c < TY; ++c)
            #pragma unroll
            for (int d = 0; d < TX; ++d) acc[a][c][d] = bv;

    for (int ci = 0; ci < cspan; ++ci) {
        const float* wr = wb + ci * 64;        // uniform -> s_load
        const float* xc = xb + ci * chs;
        #pragma unroll
        for (int jz = 0; jz < SZ; ++jz) {
            float plane[SY][SX];
            #pragma unroll
            for (int jy = 0; jy < SY; ++jy)
                load_row<SX>(xc + ((long)jz * PD + jy) * PRX, plane[jy]);
            #pragma unroll
            for (int oz = 0; oz < TZ; ++oz) {
                const int kz = jz - 2 * oz;
                if (kz < 0 || kz > 3) continue;
                #pragma unroll
                for (int jy = 0; jy < SY; ++jy) {
                    #pragma unroll
                    for (int oy = 0; oy < TY; ++oy) {
                        const int ky = jy - 2 * oy;
                        if (ky < 0 || ky > 3) continue;
                        #pragma unroll
                        for (int jx = 0; jx < SX; ++jx) {
                            #pragma unroll
                            for (int ox = 0; ox < TX; ++ox) {
                                const int kx = jx - 2 * ox;
                                if (kx < 0 || kx > 3) continue;
                                acc[oz][oy][ox] = fmaf(plane[jy][jx],
                                                       wr[(kz * 4 + ky) * 4 + kx],
                                                       acc[oz][oy][ox]);
                            }
                        }
                    }
                }
            }
        }
    }

    float* yb = y + (long)s * sstride + (long)(b * Cout + co) * OPD * OPD * OPRX;
    #pragma unroll
    for (int oz = 0; oz < TZ; ++oz)
        #pragma unroll
        for (int oy = 0; oy < TY; ++oy)
            #pragma unroll
            for (int ox = 0; ox < TX; ++ox) {
                int opz = TZ * tz + oz + po, opy = TY * ty + oy + po, opx = TX * tx + ox + po;
                float v = acc[oz][oy][ox];
                if (relu) v = fmaxf(v, 0.0f);
                yb[((long)opz * OPD + opy) * OPRX + opx] = v;
            }
}

// Combine two Cin-split partials: y = relu(p0 + p1), placed at +po in a
// (OPD,OPD,OPRX)-pitched buffer. p layout: tight (C_, D^3) per split.
__global__ __launch_bounds__(256)
void combine2_relu(const float* __restrict__ p, float* __restrict__ y,
                   int C_, int D, int OPD, int OPRX, int po, long sstride)
{
    long N = (long)C_ * D * D * D;
    long idx = (long)blockIdx.x * blockDim.x + threadIdx.x;
    if (idx >= N) return;
    int x_ = (int)(idx % D); long t = idx / D;
    int y_ = (int)(t % D); t /= D;
    int z_ = (int)(t % D); int c = (int)(t / D);
    float v = p[idx] + p[idx + sstride];
    y[(((long)c * OPD + z_ + po) * OPD + (y_ + po)) * OPRX + (x_ + po)] = fmaxf(v, 0.0f);
}

// ---------------- 1x1 conv ----------------
__global__ __launch_bounds__(128)
void conv1x1_b(const float* __restrict__ x, const float* __restrict__ w,
               const float* __restrict__ bias, float* __restrict__ y)
{
    const int co = blockIdx.x & 255, b = blockIdx.x >> 8;
    const int s4 = (int)threadIdx.x * 4;
    const float* xb = x + (long)b * 256 * 512 + s4;
    const float* wr = w + (long)co * 256;      // uniform -> s_load
    float bv = bias[co];
    float4 acc = {bv, bv, bv, bv};
    for (int ci = 0; ci < 256; ++ci) {
        float wv = wr[ci];
        float4 xv = *(const float4*)(xb + (long)ci * 512);
        acc.x = fmaf(xv.x, wv, acc.x); acc.y = fmaf(xv.y, wv, acc.y);
        acc.z = fmaf(xv.z, wv, acc.z); acc.w = fmaf(xv.w, wv, acc.w);
    }
    *(float4*)(y + (long)(b * 256 + co) * 512 + s4) = acc;
}

// ---------------- VQ (fp32 exact; same summation order as R2-R7) ------------
__global__ void codenorm_kernel(const float* __restrict__ cb, float* __restrict__ norms)
{
    int k = blockIdx.x;
    int lane = threadIdx.x;
    float s = 0.0f;
    const float* row = cb + (long)k * 256;
    for (int d = lane; d < 256; d += 64) { float v = row[d]; s = fmaf(v, v, s); }
    for (int off = 32; off > 0; off >>= 1) s += __shfl_down(s, off);
    if (lane == 0) norms[k] = s;
}

__global__ __launch_bounds__(256)
void vq_kernel(const float* __restrict__ lat, const float* __restrict__ cb,
               const float* __restrict__ norms, unsigned short* __restrict__ q,
               float* __restrict__ idx_out)
{
    __shared__ __align__(16) float row[256];
    __shared__ float s_best[256];
    __shared__ int   s_bidx[256];
    int r = blockIdx.x;
    int t = threadIdx.x;
    row[t] = lat[(long)r * 256 + t];
    __syncthreads();

    const float4* rowv = (const float4*)row;
    float latn = 0.0f;
    #pragma unroll 4
    for (int d = 0; d < 64; ++d) {
        float4 rv = rowv[d];
        latn = fmaf(rv.x, rv.x, latn); latn = fmaf(rv.y, rv.y, latn);
        latn = fmaf(rv.z, rv.z, latn); latn = fmaf(rv.w, rv.w, latn);
    }

    float best = FLT_MAX;
    int bidx = 0x7fffffff;
    for (int j = 0; j < 4; ++j) {
        int k = t + 256 * j;
        const float4* cr = (const float4*)(cb + (long)k * 256);
        float dot = 0.0f;
        #pragma unroll 4
        for (int d = 0; d < 64; ++d) {
            float4 c = cr[d]; float4 rv = rowv[d];
            dot = fmaf(rv.x, c.x, dot); dot = fmaf(rv.y, c.y, dot);
            dot = fmaf(rv.z, c.z, dot); dot = fmaf(rv.w, c.w, dot);
        }
        float sc = latn - 2.0f * dot + norms[k];
        if (sc < best || (sc == best && k < bidx)) { best = sc; bidx = k; }
    }
    s_best[t] = best; s_bidx[t] = bidx;
    __syncthreads();
    for (int off = 128; off > 0; off >>= 1) {
        if (t < off) {
            float o = s_best[t + off]; int oi = s_bidx[t + off];
            if (o < s_best[t] || (o == s_best[t] && oi < s_bidx[t])) {
                s_best[t] = o; s_bidx[t] = oi;
            }
        }
        __syncthreads();
    }
    int bk = s_bidx[0];
    int b = r >> 9, n = r & 511;
    int zz = n >> 6, yy = (n >> 3) & 7, xx = n & 7;
    q[(long)(b * 256 + t) * 1000 + ((long)(zz + 1) * 10 + (yy + 1)) * 10 + (xx + 1)]
        = f32_to_bf16(cb[(long)bk * 256 + t]);
    if (t == 0) idx_out[r] = (float)bk;
}

// ---------------- decoder: MFMA implicit-GEMM ConvTranspose ----------------
__global__ __launch_bounds__(256)
void prep_convt_w(const float* __restrict__ w, short* __restrict__ Ap,
                  int Cin, int Cout)
{
    const int K = Cin * 8;
    long total = 8L * Cout * K;
    long idx = (long)blockIdx.x * blockDim.x + threadIdx.x;
    if (idx >= total) return;
    int k = (int)(idx % K);
    int co = (int)((idx / K) % Cout);
    int p = (int)(idx / ((long)K * Cout));
    int ci = k >> 3, a = k & 7;
    int az = (a >> 2) & 1, ay = (a >> 1) & 1, ax = a & 1;
    int pz = p >> 2, py = (p >> 1) & 1, px = p & 1;
    int kd = (1 - pz) + 2 * az, kh = (1 - py) + 2 * ay, kw = (1 - px) + 2 * ax;
    float v = w[((long)ci * Cout + co) * 64 + kd * 16 + kh * 4 + kw];
    Ap[idx] = (short)f32_to_bf16(v);
}

template <int DIN, int OPAD, typename OutT>
__global__ __launch_bounds__(256)
void convt_mfma(const unsigned short* __restrict__ Xp, const short* __restrict__ Ap,
                const float* __restrict__ bias, OutT* __restrict__ Y,
                int Cin, int Cout)
{
    constexpr int PD = DIN + 2;
    constexpr int PD3 = PD * PD * PD;
    constexpr int T = DIN >> 2;
    constexpr int NT = T * T * T;
    constexpr int OPD = 2 * DIN + 2 * OPAD;
    const int K = Cin * 8;
    const int MG = Cout >> 6;

    int bx = blockIdx.x;
    const int mg = bx % MG; bx /= MG;
    const int nt = bx % NT; bx /= NT;
    const int p = bx;
    const int pz = p >> 2, py = (p >> 1) & 1, px = p & 1;

    const int lane = threadIdx.x & 63, wave = threadIdx.x >> 6;
    const int n16 = lane & 15, quad = lane >> 4;

    const int tx = nt % T, ty = (nt / T) % T, tz = nt / (T * T);
    const int mz = tz * 4 + wave, my = ty * 4 + (n16 >> 2), mx = tx * 4 + (n16 & 3);
    const int sp = ((mz + pz) * PD + (my + py)) * PD + (mx + px);

    const unsigned short* xq = Xp + (long)quad * PD3 + sp;

    const int cobase = mg * 64;
    const short* ap0 = Ap + ((long)p * Cout + cobase + n16) * K + quad * 8;

    f32x4 acc[4];
    #pragma unroll
    for (int cb = 0; cb < 4; ++cb) {
        const float* bp = bias + cobase + cb * 16 + quad * 4;
        acc[cb][0] = bp[0]; acc[cb][1] = bp[1]; acc[cb][2] = bp[2]; acc[cb][3] = bp[3];
    }

    const int nsteps = K >> 5;
    for (int s = 0; s < nsteps; ++s) {
        bf16x8 bf;
        bf[0] = (short)xq[(PD + 1) * PD + 1];
        bf[1] = (short)xq[(PD + 1) * PD];
        bf[2] = (short)xq[PD * PD + 1];
        bf[3] = (short)xq[PD * PD];
        bf[4] = (short)xq[PD + 1];
        bf[5] = (short)xq[PD];
        bf[6] = (short)xq[1];
        bf[7] = (short)xq[0];
        #pragma unroll
        for (int cb = 0; cb < 4; ++cb) {
            bf16x8 af = *(const bf16x8*)(ap0 + (long)cb * 16 * K + s * 32);
            acc[cb] = __builtin_amdgcn_mfma_f32_16x16x32_bf16(af, bf, acc[cb], 0, 0, 0);
        }
        xq += 4 * PD3;
    }

    const int opz = 2 * mz + pz + OPAD, opy = 2 * my + py + OPAD, opx = 2 * mx + px + OPAD;
    const long spo = ((long)opz * OPD + opy) * OPD + opx;
    #pragma unroll
    for (int cb = 0; cb < 4; ++cb) {
        #pragma unroll
        for (int r = 0; r < 4; ++r) {
            int co = cobase + cb * 16 + quad * 4 + r;
            float v = fmaxf(acc[cb][r], 0.0f);
            store_act(Y + (long)co * OPD * OPD * OPD + spo, v);
        }
    }
}

// ---------------- dec4 as MFMA GEMM: M=16 (3 used), N=61^3, K=4096 ----------
__global__ __launch_bounds__(256)
void prep_dec4A(const float* __restrict__ w, short* __restrict__ Aw)
{
    int idx = blockIdx.x * 256 + (int)threadIdx.x;    // 0..65535
    int m = idx >> 12, k = idx & 4095;
    float v = (m < 3) ? w[m * 4096 + k] : 0.0f;
    Aw[idx] = (short)f32_to_bf16(v);
}

__global__ __launch_bounds__(256)
void conv_dec4_mfma(const float* __restrict__ d3, const short* __restrict__ Aw,
                    const float* __restrict__ bias, float* __restrict__ y)
{
    constexpr int D = 64, Dout = 61;
    const int oh = blockIdx.x % Dout, od = blockIdx.x / Dout;
    const int lane = (int)threadIdx.x & 63, wave = (int)threadIdx.x >> 6;
    const int n16 = lane & 15, quad = lane >> 4;
    const int ow = wave * 16 + n16;

    f32x4 acc;
    #pragma unroll
    for (int r = 0; r < 4; ++r) {
        int co = quad * 4 + r;
        acc[r] = (co < 3) ? bias[co] : 0.0f;
    }

    const short* ap = Aw + (long)n16 * 4096 + quad * 8;   // m = lane&15
    const int kd0 = quad >> 1;
    const int kh0 = (quad & 1) * 2;
    const float* base0 = d3 + ((long)(od + kd0) * D + (oh + kh0)) * D + ow;

    #pragma unroll 4
    for (int s = 0; s < 128; ++s) {
        const int ci = s >> 1;
        const float* base = base0 + ((long)ci * D + (s & 1) * 2) * D * D;
        f32x4u r0 = *(const f32x4u*)base;
        f32x4u r1 = *(const f32x4u*)(base + D);
        bf16x8 bf;
        bf[0] = (short)(__float_as_uint(r0.x) >> 16);
        bf[1] = (short)(__float_as_uint(r0.y) >> 16);
        bf[2] = (short)(__float_as_uint(r0.z) >> 16);
        bf[3] = (short)(__float_as_uint(r0.w) >> 16);
        bf[4] = (short)(__float_as_uint(r1.x) >> 16);
        bf[5] = (short)(__float_as_uint(r1.y) >> 16);
        bf[6] = (short)(__float_as_uint(r1.z) >> 16);
        bf[7] = (short)(__float_as_uint(r1.w) >> 16);
        bf16x8 af = *(const bf16x8*)(ap + s * 32);
        acc = __builtin_amdgcn_mfma_f32_16x16x32_bf16(af, bf, acc, 0, 0, 0);
    }

    if (ow < Dout && quad == 0) {
        #pragma unroll
        for (int r = 0; r < 3; ++r)
            y[((long)(r * Dout + od) * Dout + oh) * Dout + ow] = tanhf(acc[r]);
    }
}

extern "C" void kernel_launch(void* const* d_in, const int* in_sizes, int n_in,
                              void* d_out, int out_size, void* d_ws, size_t ws_size,
                              hipStream_t stream)
{
    const float* x        = (const float*)d_in[0];
    const float* enc_w1   = (const float*)d_in[1];
    const float* enc_b1   = (const float*)d_in[2];
    const float* enc_w2   = (const float*)d_in[3];
    const float* enc_b2   = (const float*)d_in[4];
    const float* enc_w3   = (const float*)d_in[5];
    const float* enc_b3   = (const float*)d_in[6];
    const float* enc_w4   = (const float*)d_in[7];
    const float* enc_b4   = (const float*)d_in[8];
    const float* codebook = (const float*)d_in[9];
    const float* dec_w1   = (const float*)d_in[10];
    const float* dec_b1   = (const float*)d_in[11];
    const float* dec_w2   = (const float*)d_in[12];
    const float* dec_b2   = (const float*)d_in[13];
    const float* dec_w3   = (const float*)d_in[14];
    const float* dec_b3   = (const float*)d_in[15];
    const float* dec_w4   = (const float*)d_in[16];
    const float* dec_b4   = (const float*)d_in[17];

    float* out = (float*)d_out;
    float* idx_out = out + 2L * 3 * 61 * 61 * 61;

    // ---- workspace (byte offsets; persistent | overlapped arena) ----
    char* wsb = (char*)d_ws;
    float*          cn  = (float*)wsb;                       //     4,096 B
    unsigned short* qp  = (unsigned short*)(wsb + 4096);     // 1,024,000 B
    short*          Ap1 = (short*)(wsb + 1028096);           // 8,388,608 B
    short*          Ap2 = (short*)(wsb + 9416704);           // 4,194,304 B
    short*          Ap3 = (short*)(wsb + 13611008);          // 1,048,576 B
    short*          Aw4 = (short*)(wsb + 14659584);          //   131,072 B
    char* arena = wsb + 14790656;
    // encoder phase (fp32, x-pitched padded):
    float* xp  = (float*)arena;                  // (2,3,66,66,68)  = 1,777,248 f
    float* h1p = (float*)arena + 1777248;        // (2,64,34,34,36) = 5,326,848 f
    float* h2p = (float*)arena + 7104096;        // (2,128,18,18,20)= 1,658,880 f
    float* h3  = (float*)arena + 8762976;        // (2,256,8^3)     =   262,144 f
    float* lat = (float*)arena + 9025120;        //                   262,144 f
    float* pp2 = (float*)arena + 9287264;        // enc2 partials 2x(2,128,16^3) = 4,194,304 f
    float* pp3 = (float*)arena + 13481568;       // enc3 partials 2x(2,256,8^3)  =   524,288 f
    // (encoder phase peak = 14,005,856 f = 56.0 MB)
    // decoder phase (after VQ; overlaps encoder buffers):
    unsigned short* d1 = (unsigned short*)arena;               // (256,18^3) bf16
    unsigned short* d2 = (unsigned short*)(arena + 2985984);   // (128,34^3) bf16
    float*          d3 = (float*)(arena + 13047808);           // (64,64^3) fp32
    // arena peak 80.2 MB; total ~94.9 MB (< 101.7 MB proven in R1)

    dim3 blk(256);
    auto nblk = [](long n) { return dim3((unsigned)((n + 255) / 256)); };

    // ---- decoder weight pre-gather ----
    prep_convt_w<<<nblk(8L * 256 * 2048), blk, 0, stream>>>(dec_w1, Ap1, 256, 256);
    prep_convt_w<<<nblk(8L * 128 * 2048), blk, 0, stream>>>(dec_w2, Ap2, 256, 128);
    prep_convt_w<<<nblk(8L * 64 * 1024), blk, 0, stream>>>(dec_w3, Ap3, 128, 64);
    prep_dec4A<<<dim3(256), blk, 0, stream>>>(dec_w4, Aw4);

    // ---- encoder (fp32, pitched) ----
    pad_input_p<<<nblk(6L * 66 * 66 * 68), blk, 0, stream>>>(x, xp, 6, 64, 68);
    zero_halo_p<<<nblk(128L * 34 * 34 * 36), blk, 0, stream>>>(h1p, 128, 34, 36);
    // enc1 (R5 config, no split): tile(2,2,4): grid = 2*64*8 = 1024
    conv_s2_tile<2, 2, 4><<<dim3(2 * 64 * 8), blk, 0, stream>>>(
        xp, enc_w1, enc_b1, h1p, 2, 3, 3, 1, 64, 32, 66, 68, 8, 34, 36, 1, 1, 0);
    zero_halo_p<<<nblk(256L * 18 * 18 * 20), blk, 0, stream>>>(h2p, 256, 18, 20);
    // enc2: R5 tile(1,2,2) + Cin-split x2: grid = 2*128*2*4 = 2048, partials tight 16^3
    conv_s2_tile<1, 2, 2><<<dim3(2 * 128 * 2 * 4), blk, 0, stream>>>(
        h1p, enc_w2, enc_b2, pp2, 2, 64, 32, 2, 128, 16, 34, 36, 4, 16, 16, 0, 0,
        2L * 128 * 4096);
    combine2_relu<<<nblk(2L * 128 * 4096), blk, 0, stream>>>(
        pp2, h2p, 256, 16, 18, 20, 1, 2L * 128 * 4096);
    // enc3: tile(1,1,2) + Cin-split x2: grid = 2*256*2*1 = 1024, partials tight 8^3
    conv_s2_tile<1, 1, 2><<<dim3(2 * 256 * 2), blk, 0, stream>>>(
        h2p, enc_w3, enc_b3, pp3, 2, 128, 64, 2, 256, 8, 18, 20, 1, 8, 8, 0, 0,
        2L * 256 * 512);
    combine2_relu<<<nblk(2L * 256 * 512), blk, 0, stream>>>(
        pp3, h3, 512, 8, 8, 8, 0, 2L * 256 * 512);
    conv1x1_b<<<dim3(512), dim3(128), 0, stream>>>(h3, enc_w4, enc_b4, lat);

    // ---- VQ (fp32 exact) ----
    codenorm_kernel<<<dim3(1024), dim3(64), 0, stream>>>(codebook, cn);
    zero_halo_t<unsigned short><<<nblk(512L * 10 * 10 * 10), blk, 0, stream>>>(qp, 512, 10);
    vq_kernel<<<dim3(1024), blk, 0, stream>>>(lat, codebook, cn, qp, idx_out);

    // ---- decoder halos ----
    zero_halo_t<unsigned short><<<nblk(256L * 18 * 18 * 18), blk, 0, stream>>>(d1, 256, 18);
    zero_halo_t<unsigned short><<<nblk(128L * 34 * 34 * 34), blk, 0, stream>>>(d2, 128, 34);

    // ---- decoder (MFMA) per batch ----
    for (int b = 0; b < 2; ++b) {
        const unsigned short* qb = qp + (long)b * 256 * 1000;
        float* outb = out + (long)b * 3 * 226981;
        convt_mfma<8, 1, unsigned short><<<dim3(8 * 8 * 4), blk, 0, stream>>>(
            qb, Ap1, dec_b1, d1, 256, 256);
        convt_mfma<16, 1, unsigned short><<<dim3(8 * 64 * 2), blk, 0, stream>>>(
            d1, Ap2, dec_b2, d2, 256, 128);
        convt_mfma<32, 0, float><<<dim3(8 * 512), blk, 0, stream>>>(
            d2, Ap3, dec_b3, d3, 128, 64);
        conv_dec4_mfma<<<dim3(61 * 61), blk, 0, stream>>>(d3, Aw4, dec_b4, outb);
    }
}

// Round 9
// 2266.182 us; speedup vs baseline: 1.4729x; 1.2180x over previous
//
#include <hip/hip_runtime.h>
#include <cfloat>
#include <cmath>

// ---------------------------------------------------------------------------
// Round 8: encoder convs -> MFMA implicit GEMM with bf16 hi/lo pair inputs
// (x ~ hi+lo, w ~ hi+lo; x*w ~ hi*hi + hi*lo + lo*hi via 3 MFMAs => ~3e-5 rel
// accuracy, safe for the exact fp32 VQ argmin). Activations stored as two
// bf16 planes, split in producer epilogues. Gather structure mirrors the
// verified dec4 MFMA kernel. Decoder unchanged from R4-R8.
// ---------------------------------------------------------------------------

using f32x4  = __attribute__((ext_vector_type(4))) float;
using bf16x8 = __attribute__((ext_vector_type(8))) short;
typedef float f32x4u __attribute__((ext_vector_type(4), aligned(4)));
typedef unsigned short u16x4u __attribute__((ext_vector_type(4), aligned(4)));

__device__ __forceinline__ unsigned short f32_to_bf16(float f) {
    unsigned int u = __float_as_uint(f);
    u += 0x7fffu + ((u >> 16) & 1u);          // round-to-nearest-even
    return (unsigned short)(u >> 16);
}
__device__ __forceinline__ void split_bf16(float v, unsigned short& h, unsigned short& l) {
    h = f32_to_bf16(v);
    float hf = __uint_as_float((unsigned)h << 16);
    l = f32_to_bf16(v - hf);
}
__device__ __forceinline__ void store_act(float* p, float v) { *p = v; }
__device__ __forceinline__ void store_act(unsigned short* p, float v) { *p = f32_to_bf16(v); }

__device__ __forceinline__ bf16x8 pack_b(u16x4u r0, u16x4u r1) {
    bf16x8 b;
    b[0] = (short)r0[0]; b[1] = (short)r0[1]; b[2] = (short)r0[2]; b[3] = (short)r0[3];
    b[4] = (short)r1[0]; b[5] = (short)r1[1]; b[6] = (short)r1[2]; b[7] = (short)r1[3];
    return b;
}

// ---------------- prep: weight hi/lo split (flat (Cout,Cin,64) = GEMM A) ----
__global__ __launch_bounds__(256)
void prep_split_w(const float* __restrict__ w, short* __restrict__ whi,
                  short* __restrict__ wlo, long total)
{
    long idx = (long)blockIdx.x * blockDim.x + threadIdx.x;
    if (idx >= total) return;
    unsigned short h, l;
    split_bf16(w[idx], h, l);
    whi[idx] = (short)h; wlo[idx] = (short)l;
}

// ---------------- pad input -> hi/lo bf16 pitched planes --------------------
__global__ __launch_bounds__(256)
void pad_input_split(const float* __restrict__ x, unsigned short* __restrict__ xhi,
                     unsigned short* __restrict__ xlo)
{
    const int D = 64, PD = 66, PRX = 68, BC = 6;
    long total = (long)BC * PD * PD * PRX;
    long idx = (long)blockIdx.x * blockDim.x + threadIdx.x;
    if (idx >= total) return;
    int px = (int)(idx % PRX); long t = idx / PRX;
    int py = (int)(t % PD); t /= PD;
    int pz = (int)(t % PD); int c = (int)(t / PD);
    int ix = px - 1, iy = py - 1, iz = pz - 1;
    float v = 0.0f;
    if ((unsigned)ix < (unsigned)D && (unsigned)iy < (unsigned)D && (unsigned)iz < (unsigned)D)
        v = x[(((long)c * D + iz) * D + iy) * D + ix];
    unsigned short h, l;
    split_bf16(v, h, l);
    xhi[idx] = h; xlo[idx] = l;
}

// Zero halo + pitch extras of (C, PD, PD, PRX) ushort buffer.
__global__ __launch_bounds__(256)
void zero_halo_ps(unsigned short* __restrict__ p, int C, int PD, int PRX)
{
    long total = (long)C * PD * PD * PRX;
    long idx = (long)blockIdx.x * blockDim.x + threadIdx.x;
    if (idx >= total) return;
    int px = (int)(idx % PRX); long t = idx / PRX;
    int py = (int)(t % PD); t /= PD;
    int pz = (int)(t % PD);
    if (px == 0 || px >= PD - 1 || py == 0 || py == PD - 1 || pz == 0 || pz == PD - 1)
        p[idx] = 0;
}

// Unpitched halo zero (decoder bf16 activations, qp).
template <typename T>
__global__ __launch_bounds__(256) void zero_halo_t(T* __restrict__ p, int C, int PD)
{
    long total = (long)C * PD * PD * PD;
    long idx = (long)blockIdx.x * blockDim.x + threadIdx.x;
    if (idx >= total) return;
    int px = (int)(idx % PD); long t = idx / PD;
    int py = (int)(t % PD); t /= PD;
    int pz = (int)(t % PD);
    if (px == 0 || px == PD - 1 || py == 0 || py == PD - 1 || pz == 0 || pz == PD - 1)
        p[idx] = (T)0;
}

// ---------------------------------------------------------------------------
// Conv3d k4 s2 p1 as MFMA implicit GEMM, bf16 hi/lo pair inputs.
// M = Cout, N = B*Dout^3, K = Cin*64 (k = ci*64 + kd*16 + kh*4 + kw).
// Per-lane B-frag: padded input at (2od+kd0, 2oh+kh0(+1), 2ow..2ow+3),
// kd0 = (sg&1)*2 + (quad>>1), kh0 = (quad&1)*2 (same octet map as dec4).
// Waves: MWAVES = COUT/(16*MTW) waves cover M; RPB = 4/MWAVES rows per block.
// OUTSPLIT=1: write relu'd hi/lo bf16 pitched; else fp32 partial (K-split).
// ---------------------------------------------------------------------------
template <int CIN, int COUT, int DOUT, int PD, int PRX, int MTW, int OWT,
          int OWHALF, int KSPLIT, int OUTSPLIT>
__global__ __launch_bounds__(256)
void conv_s2_mfma(const unsigned short* __restrict__ xhi,
                  const unsigned short* __restrict__ xlo,
                  const short* __restrict__ Whi, const short* __restrict__ Wlo,
                  const float* __restrict__ bias,
                  unsigned short* __restrict__ yhi, unsigned short* __restrict__ ylo,
                  float* __restrict__ yf,
                  int OPD, int OPRX, int po, long sstride)
{
    constexpr int K = CIN * 64;
    constexpr int MWAVES = COUT / (16 * MTW);
    constexpr int RPB = 4 / MWAVES;
    constexpr int KN = (CIN * 2) / KSPLIT;

    int bx = blockIdx.x;
    const int ks = (KSPLIT > 1) ? (bx % KSPLIT) : 0;
    const int rowblk = (KSPLIT > 1) ? (bx / KSPLIT) : bx;
    const int lane = (int)threadIdx.x & 63, w = (int)threadIdx.x >> 6;
    const int mi = (MWAVES == 4) ? w : 0;
    const int ri = (MWAVES == 4) ? 0 : w;
    const int rowid = rowblk * RPB + ri;
    const int n16 = lane & 15, quad = lane >> 4;

    int b, od, oh, ow;
    if (OWHALF) {
        constexpr int NOH = DOUT / 2;
        const int ohb = rowid % NOH; int t = rowid / NOH;
        od = t % DOUT; b = t / DOUT;
        oh = ohb * 2 + (n16 >> 3);
        ow = n16 & 7;
    } else {
        const int owt = rowid % OWT; int t = rowid / OWT;
        oh = t % DOUT; t /= DOUT;
        od = t % DOUT; b = t / DOUT;
        ow = owt * 16 + n16;
    }

    const int co0 = mi * (MTW * 16);

    f32x4 acc[MTW];
    #pragma unroll
    for (int mt = 0; mt < MTW; ++mt)
        #pragma unroll
        for (int r = 0; r < 4; ++r) {
            int co = co0 + mt * 16 + quad * 4 + r;
            acc[mt][r] = (ks == 0) ? bias[co] : 0.0f;
        }

    const int sg0 = ks * KN;                   // always even
    const long chs = (long)PD * PD * PRX;
    long off = ((long)(b * CIN + (sg0 >> 1)) * PD + (2 * od + (quad >> 1))) * PD * PRX
             + (long)(2 * oh + (quad & 1) * 2) * PRX + 2 * ow;
    const unsigned short* phi = xhi + off;
    const unsigned short* plo = xlo + off;
    const long incA = 2L * PD * PRX;           // sg even -> odd: kd0 += 2
    const long incB = chs - 2L * PD * PRX;     // sg odd -> even: ci++, kd0 -= 2

    const short* a0h = Whi + (long)(co0 + n16) * K + sg0 * 32 + quad * 8;
    const short* a0l = Wlo + (long)(co0 + n16) * K + sg0 * 32 + quad * 8;

    #pragma unroll 2
    for (int s = 0; s < KN; ++s) {
        u16x4u h0 = *(const u16x4u*)phi;
        u16x4u h1 = *(const u16x4u*)(phi + PRX);
        u16x4u l0 = *(const u16x4u*)plo;
        u16x4u l1 = *(const u16x4u*)(plo + PRX);
        bf16x8 bhi = pack_b(h0, h1);
        bf16x8 blo = pack_b(l0, l1);
        #pragma unroll
        for (int mt = 0; mt < MTW; ++mt) {
            bf16x8 ah = *(const bf16x8*)(a0h + (long)mt * 16 * K + s * 32);
            bf16x8 al = *(const bf16x8*)(a0l + (long)mt * 16 * K + s * 32);
            acc[mt] = __builtin_amdgcn_mfma_f32_16x16x32_bf16(ah, bhi, acc[mt], 0, 0, 0);
            acc[mt] = __builtin_amdgcn_mfma_f32_16x16x32_bf16(ah, blo, acc[mt], 0, 0, 0);
            acc[mt] = __builtin_amdgcn_mfma_f32_16x16x32_bf16(al, bhi, acc[mt], 0, 0, 0);
        }
        long inc = (s & 1) ? incB : incA;
        phi += inc; plo += inc;
    }

    if (OUTSPLIT) {
        #pragma unroll
        for (int mt = 0; mt < MTW; ++mt)
            #pragma unroll
            for (int r = 0; r < 4; ++r) {
                int co = co0 + mt * 16 + quad * 4 + r;
                float v = fmaxf(acc[mt][r], 0.0f);
                unsigned short h, l;
                split_bf16(v, h, l);
                long o = (((long)(b * COUT + co) * OPD + od + po) * OPD + oh + po) * OPRX
                       + ow + po;
                yhi[o] = h; ylo[o] = l;
            }
    } else {
        #pragma unroll
        for (int mt = 0; mt < MTW; ++mt)
            #pragma unroll
            for (int r = 0; r < 4; ++r) {
                int co = co0 + mt * 16 + quad * 4 + r;
                long o = (long)ks * sstride
                       + (((long)(b * COUT + co) * OPD + od) * OPD + oh) * OPRX + ow;
                yf[o] = acc[mt][r];
            }
    }
}

// Combine 4 K-split partials with ReLU (tight layout).
__global__ __launch_bounds__(256)
void combine4_relu(const float* __restrict__ p, float* __restrict__ y, long N, long ss)
{
    long idx = (long)blockIdx.x * blockDim.x + threadIdx.x;
    if (idx >= N) return;
    float v = p[idx] + p[idx + ss] + p[idx + 2 * ss] + p[idx + 3 * ss];
    y[idx] = fmaxf(v, 0.0f);
}

// ---------------- 1x1 conv (fp32 exact) ----------------
__global__ __launch_bounds__(128)
void conv1x1_b(const float* __restrict__ x, const float* __restrict__ w,
               const float* __restrict__ bias, float* __restrict__ y)
{
    const int co = blockIdx.x & 255, b = blockIdx.x >> 8;
    const int s4 = (int)threadIdx.x * 4;
    const float* xb = x + (long)b * 256 * 512 + s4;
    const float* wr = w + (long)co * 256;      // uniform -> s_load
    float bv = bias[co];
    float4 acc = {bv, bv, bv, bv};
    for (int ci = 0; ci < 256; ++ci) {
        float wv = wr[ci];
        float4 xv = *(const float4*)(xb + (long)ci * 512);
        acc.x = fmaf(xv.x, wv, acc.x); acc.y = fmaf(xv.y, wv, acc.y);
        acc.z = fmaf(xv.z, wv, acc.z); acc.w = fmaf(xv.w, wv, acc.w);
    }
    *(float4*)(y + (long)(b * 256 + co) * 512 + s4) = acc;
}

// ---------------- VQ (fp32 exact; same summation order as R2-R8) ------------
__global__ void codenorm_kernel(const float* __restrict__ cb, float* __restrict__ norms)
{
    int k = blockIdx.x;
    int lane = threadIdx.x;
    float s = 0.0f;
    const float* row = cb + (long)k * 256;
    for (int d = lane; d < 256; d += 64) { float v = row[d]; s = fmaf(v, v, s); }
    for (int off = 32; off > 0; off >>= 1) s += __shfl_down(s, off);
    if (lane == 0) norms[k] = s;
}

__global__ __launch_bounds__(256)
void vq_kernel(const float* __restrict__ lat, const float* __restrict__ cb,
               const float* __restrict__ norms, unsigned short* __restrict__ q,
               float* __restrict__ idx_out)
{
    __shared__ __align__(16) float row[256];
    __shared__ float s_best[256];
    __shared__ int   s_bidx[256];
    int r = blockIdx.x;
    int t = threadIdx.x;
    row[t] = lat[(long)r * 256 + t];
    __syncthreads();

    const float4* rowv = (const float4*)row;
    float latn = 0.0f;
    #pragma unroll 4
    for (int d = 0; d < 64; ++d) {
        float4 rv = rowv[d];
        latn = fmaf(rv.x, rv.x, latn); latn = fmaf(rv.y, rv.y, latn);
        latn = fmaf(rv.z, rv.z, latn); latn = fmaf(rv.w, rv.w, latn);
    }

    float best = FLT_MAX;
    int bidx = 0x7fffffff;
    for (int j = 0; j < 4; ++j) {
        int k = t + 256 * j;
        const float4* cr = (const float4*)(cb + (long)k * 256);
        float dot = 0.0f;
        #pragma unroll 4
        for (int d = 0; d < 64; ++d) {
            float4 c = cr[d]; float4 rv = rowv[d];
            dot = fmaf(rv.x, c.x, dot); dot = fmaf(rv.y, c.y, dot);
            dot = fmaf(rv.z, c.z, dot); dot = fmaf(rv.w, c.w, dot);
        }
        float sc = latn - 2.0f * dot + norms[k];
        if (sc < best || (sc == best && k < bidx)) { best = sc; bidx = k; }
    }
    s_best[t] = best; s_bidx[t] = bidx;
    __syncthreads();
    for (int off = 128; off > 0; off >>= 1) {
        if (t < off) {
            float o = s_best[t + off]; int oi = s_bidx[t + off];
            if (o < s_best[t] || (o == s_best[t] && oi < s_bidx[t])) {
                s_best[t] = o; s_bidx[t] = oi;
            }
        }
        __syncthreads();
    }
    int bk = s_bidx[0];
    int b = r >> 9, n = r & 511;
    int zz = n >> 6, yy = (n >> 3) & 7, xx = n & 7;
    q[(long)(b * 256 + t) * 1000 + ((long)(zz + 1) * 10 + (yy + 1)) * 10 + (xx + 1)]
        = f32_to_bf16(cb[(long)bk * 256 + t]);
    if (t == 0) idx_out[r] = (float)bk;
}

// ---------------- decoder: MFMA implicit-GEMM ConvTranspose (unchanged) -----
__global__ __launch_bounds__(256)
void prep_convt_w(const float* __restrict__ w, short* __restrict__ Ap,
                  int Cin, int Cout)
{
    const int K = Cin * 8;
    long total = 8L * Cout * K;
    long idx = (long)blockIdx.x * blockDim.x + threadIdx.x;
    if (idx >= total) return;
    int k = (int)(idx % K);
    int co = (int)((idx / K) % Cout);
    int p = (int)(idx / ((long)K * Cout));
    int ci = k >> 3, a = k & 7;
    int az = (a >> 2) & 1, ay = (a >> 1) & 1, ax = a & 1;
    int pz = p >> 2, py = (p >> 1) & 1, px = p & 1;
    int kd = (1 - pz) + 2 * az, kh = (1 - py) + 2 * ay, kw = (1 - px) + 2 * ax;
    float v = w[((long)ci * Cout + co) * 64 + kd * 16 + kh * 4 + kw];
    Ap[idx] = (short)f32_to_bf16(v);
}

template <int DIN, int OPAD, typename OutT>
__global__ __launch_bounds__(256)
void convt_mfma(const unsigned short* __restrict__ Xp, const short* __restrict__ Ap,
                const float* __restrict__ bias, OutT* __restrict__ Y,
                int Cin, int Cout)
{
    constexpr int PD = DIN + 2;
    constexpr int PD3 = PD * PD * PD;
    constexpr int T = DIN >> 2;
    constexpr int NT = T * T * T;
    constexpr int OPD = 2 * DIN + 2 * OPAD;
    const int K = Cin * 8;
    const int MG = Cout >> 6;

    int bx = blockIdx.x;
    const int mg = bx % MG; bx /= MG;
    const int nt = bx % NT; bx /= NT;
    const int p = bx;
    const int pz = p >> 2, py = (p >> 1) & 1, px = p & 1;

    const int lane = threadIdx.x & 63, wave = threadIdx.x >> 6;
    const int n16 = lane & 15, quad = lane >> 4;

    const int tx = nt % T, ty = (nt / T) % T, tz = nt / (T * T);
    const int mz = tz * 4 + wave, my = ty * 4 + (n16 >> 2), mx = tx * 4 + (n16 & 3);
    const int sp = ((mz + pz) * PD + (my + py)) * PD + (mx + px);

    const unsigned short* xq = Xp + (long)quad * PD3 + sp;

    const int cobase = mg * 64;
    const short* ap0 = Ap + ((long)p * Cout + cobase + n16) * K + quad * 8;

    f32x4 acc[4];
    #pragma unroll
    for (int cb = 0; cb < 4; ++cb) {
        const float* bp = bias + cobase + cb * 16 + quad * 4;
        acc[cb][0] = bp[0]; acc[cb][1] = bp[1]; acc[cb][2] = bp[2]; acc[cb][3] = bp[3];
    }

    const int nsteps = K >> 5;
    for (int s = 0; s < nsteps; ++s) {
        bf16x8 bf;
        bf[0] = (short)xq[(PD + 1) * PD + 1];
        bf[1] = (short)xq[(PD + 1) * PD];
        bf[2] = (short)xq[PD * PD + 1];
        bf[3] = (short)xq[PD * PD];
        bf[4] = (short)xq[PD + 1];
        bf[5] = (short)xq[PD];
        bf[6] = (short)xq[1];
        bf[7] = (short)xq[0];
        #pragma unroll
        for (int cb = 0; cb < 4; ++cb) {
            bf16x8 af = *(const bf16x8*)(ap0 + (long)cb * 16 * K + s * 32);
            acc[cb] = __builtin_amdgcn_mfma_f32_16x16x32_bf16(af, bf, acc[cb], 0, 0, 0);
        }
        xq += 4 * PD3;
    }

    const int opz = 2 * mz + pz + OPAD, opy = 2 * my + py + OPAD, opx = 2 * mx + px + OPAD;
    const long spo = ((long)opz * OPD + opy) * OPD + opx;
    #pragma unroll
    for (int cb = 0; cb < 4; ++cb) {
        #pragma unroll
        for (int r = 0; r < 4; ++r) {
            int co = cobase + cb * 16 + quad * 4 + r;
            float v = fmaxf(acc[cb][r], 0.0f);
            store_act(Y + (long)co * OPD * OPD * OPD + spo, v);
        }
    }
}

// ---------------- dec4 as MFMA GEMM (unchanged) ----------------
__global__ __launch_bounds__(256)
void prep_dec4A(const float* __restrict__ w, short* __restrict__ Aw)
{
    int idx = blockIdx.x * 256 + (int)threadIdx.x;    // 0..65535
    int m = idx >> 12, k = idx & 4095;
    float v = (m < 3) ? w[m * 4096 + k] : 0.0f;
    Aw[idx] = (short)f32_to_bf16(v);
}

__global__ __launch_bounds__(256)
void conv_dec4_mfma(const float* __restrict__ d3, const short* __restrict__ Aw,
                    const float* __restrict__ bias, float* __restrict__ y)
{
    constexpr int D = 64, Dout = 61;
    const int oh = blockIdx.x % Dout, od = blockIdx.x / Dout;
    const int lane = (int)threadIdx.x & 63, wave = (int)threadIdx.x >> 6;
    const int n16 = lane & 15, quad = lane >> 4;
    const int ow = wave * 16 + n16;

    f32x4 acc;
    #pragma unroll
    for (int r = 0; r < 4; ++r) {
        int co = quad * 4 + r;
        acc[r] = (co < 3) ? bias[co] : 0.0f;
    }

    const short* ap = Aw + (long)n16 * 4096 + quad * 8;   // m = lane&15
    const int kd0 = quad >> 1;
    const int kh0 = (quad & 1) * 2;
    const float* base0 = d3 + ((long)(od + kd0) * D + (oh + kh0)) * D + ow;

    #pragma unroll 4
    for (int s = 0; s < 128; ++s) {
        const int ci = s >> 1;
        const float* base = base0 + ((long)ci * D + (s & 1) * 2) * D * D;
        f32x4u r0 = *(const f32x4u*)base;
        f32x4u r1 = *(const f32x4u*)(base + D);
        bf16x8 bf;
        bf[0] = (short)(__float_as_uint(r0.x) >> 16);
        bf[1] = (short)(__float_as_uint(r0.y) >> 16);
        bf[2] = (short)(__float_as_uint(r0.z) >> 16);
        bf[3] = (short)(__float_as_uint(r0.w) >> 16);
        bf[4] = (short)(__float_as_uint(r1.x) >> 16);
        bf[5] = (short)(__float_as_uint(r1.y) >> 16);
        bf[6] = (short)(__float_as_uint(r1.z) >> 16);
        bf[7] = (short)(__float_as_uint(r1.w) >> 16);
        bf16x8 af = *(const bf16x8*)(ap + s * 32);
        acc = __builtin_amdgcn_mfma_f32_16x16x32_bf16(af, bf, acc, 0, 0, 0);
    }

    if (ow < Dout && quad == 0) {
        #pragma unroll
        for (int r = 0; r < 3; ++r)
            y[((long)(r * Dout + od) * Dout + oh) * Dout + ow] = tanhf(acc[r]);
    }
}

extern "C" void kernel_launch(void* const* d_in, const int* in_sizes, int n_in,
                              void* d_out, int out_size, void* d_ws, size_t ws_size,
                              hipStream_t stream)
{
    const float* x        = (const float*)d_in[0];
    const float* enc_w1   = (const float*)d_in[1];
    const float* enc_b1   = (const float*)d_in[2];
    const float* enc_w2   = (const float*)d_in[3];
    const float* enc_b2   = (const float*)d_in[4];
    const float* enc_w3   = (const float*)d_in[5];
    const float* enc_b3   = (const float*)d_in[6];
    const float* enc_w4   = (const float*)d_in[7];
    const float* enc_b4   = (const float*)d_in[8];
    const float* codebook = (const float*)d_in[9];
    const float* dec_w1   = (const float*)d_in[10];
    const float* dec_b1   = (const float*)d_in[11];
    const float* dec_w2   = (const float*)d_in[12];
    const float* dec_b2   = (const float*)d_in[13];
    const float* dec_w3   = (const float*)d_in[14];
    const float* dec_b3   = (const float*)d_in[15];
    const float* dec_w4   = (const float*)d_in[16];
    const float* dec_b4   = (const float*)d_in[17];

    float* out = (float*)d_out;
    float* idx_out = out + 2L * 3 * 61 * 61 * 61;

    // ---- workspace (byte offsets) ----
    char* wsb = (char*)d_ws;
    float*          cn   = (float*)wsb;                        //      4,096
    unsigned short* qp   = (unsigned short*)(wsb + 4096);      //  1,024,000
    short*          Ap1  = (short*)(wsb + 1028096);            //  8,388,608
    short*          Ap2  = (short*)(wsb + 9416704);            //  4,194,304
    short*          Ap3  = (short*)(wsb + 13611008);           //  1,048,576
    short*          Aw4  = (short*)(wsb + 14659584);           //    131,072
    short*          W1hi = (short*)(wsb + 14790656);           //     24,576
    short*          W1lo = (short*)(wsb + 14815232);           //     24,576
    short*          W2hi = (short*)(wsb + 14839808);           //  1,048,576
    short*          W2lo = (short*)(wsb + 15888384);           //  1,048,576
    short*          W3hi = (short*)(wsb + 16936960);           //  4,194,304
    short*          W3lo = (short*)(wsb + 21131264);           //  4,194,304
    char* arena = wsb + 25325568;
    // encoder phase:
    unsigned short* xphi = (unsigned short*)arena;                    // (2,3,66,66,68)
    unsigned short* xplo = (unsigned short*)(arena + 3554496);
    unsigned short* h1hi = (unsigned short*)(arena + 7108992);        // (2,64,34,34,36)
    unsigned short* h1lo = (unsigned short*)(arena + 17762688);
    unsigned short* h2hi = (unsigned short*)(arena + 28416384);       // (2,128,18,18,20)
    unsigned short* h2lo = (unsigned short*)(arena + 31734144);
    float*          pp3  = (float*)(arena + 35051904);                // 4x(2,256,8^3)
    float*          h3   = (float*)(arena + 39246208);                // (2,256,512)
    float*          lat  = (float*)(arena + 40294784);                // (2,256,512)
    // decoder phase (after VQ; overlaps encoder buffers):
    unsigned short* d1 = (unsigned short*)arena;                      // (256,18^3) bf16
    unsigned short* d2 = (unsigned short*)(arena + 2985984);          // (128,34^3) bf16
    float*          d3 = (float*)(arena + 13047808);                  // (64,64^3) fp32
    // arena peak 80.2 MB; total 105.5 MB (< 112.2 MB proven in R0)

    dim3 blk(256);
    auto nblk = [](long n) { return dim3((unsigned)((n + 255) / 256)); };

    // ---- weight prep ----
    prep_convt_w<<<nblk(8L * 256 * 2048), blk, 0, stream>>>(dec_w1, Ap1, 256, 256);
    prep_convt_w<<<nblk(8L * 128 * 2048), blk, 0, stream>>>(dec_w2, Ap2, 256, 128);
    prep_convt_w<<<nblk(8L * 64 * 1024), blk, 0, stream>>>(dec_w3, Ap3, 128, 64);
    prep_dec4A<<<dim3(256), blk, 0, stream>>>(dec_w4, Aw4);
    prep_split_w<<<nblk(12288), blk, 0, stream>>>(enc_w1, W1hi, W1lo, 12288);
    prep_split_w<<<nblk(524288), blk, 0, stream>>>(enc_w2, W2hi, W2lo, 524288);
    prep_split_w<<<nblk(2097152), blk, 0, stream>>>(enc_w3, W3hi, W3lo, 2097152);

    // ---- encoder (MFMA, bf16-pair) ----
    pad_input_split<<<nblk(6L * 66 * 66 * 68), blk, 0, stream>>>(x, xphi, xplo);
    zero_halo_ps<<<nblk(128L * 34 * 34 * 36), blk, 0, stream>>>(h1hi, 128, 34, 36);
    zero_halo_ps<<<nblk(128L * 34 * 34 * 36), blk, 0, stream>>>(h1lo, 128, 34, 36);
    // enc1: rows = 2*32*32*2 = 4096, RPB=4 -> 1024 blocks
    conv_s2_mfma<3, 64, 32, 66, 68, 4, 2, 0, 1, 1><<<dim3(1024), blk, 0, stream>>>(
        xphi, xplo, W1hi, W1lo, enc_b1, h1hi, h1lo, nullptr, 34, 36, 1, 0);
    zero_halo_ps<<<nblk(256L * 18 * 18 * 20), blk, 0, stream>>>(h2hi, 256, 18, 20);
    zero_halo_ps<<<nblk(256L * 18 * 18 * 20), blk, 0, stream>>>(h2lo, 256, 18, 20);
    // enc2: rows = 2*16*16 = 512, MWAVES=4 -> 512 blocks
    conv_s2_mfma<64, 128, 16, 34, 36, 2, 1, 0, 1, 1><<<dim3(512), blk, 0, stream>>>(
        h1hi, h1lo, W2hi, W2lo, enc_b2, h2hi, h2lo, nullptr, 18, 20, 1, 0);
    // enc3: rows = 2*8*4 = 64, KSPLIT=4 -> 256 blocks, fp32 partials
    conv_s2_mfma<128, 256, 8, 18, 20, 4, 1, 1, 4, 0><<<dim3(256), blk, 0, stream>>>(
        h2hi, h2lo, W3hi, W3lo, enc_b3, nullptr, nullptr, pp3, 8, 8, 0, 262144);
    combine4_relu<<<nblk(262144), blk, 0, stream>>>(pp3, h3, 262144, 262144);
    conv1x1_b<<<dim3(512), dim3(128), 0, stream>>>(h3, enc_w4, enc_b4, lat);

    // ---- VQ (fp32 exact) ----
    codenorm_kernel<<<dim3(1024), dim3(64), 0, stream>>>(codebook, cn);
    zero_halo_t<unsigned short><<<nblk(512L * 10 * 10 * 10), blk, 0, stream>>>(qp, 512, 10);
    vq_kernel<<<dim3(1024), blk, 0, stream>>>(lat, codebook, cn, qp, idx_out);

    // ---- decoder halos ----
    zero_halo_t<unsigned short><<<nblk(256L * 18 * 18 * 18), blk, 0, stream>>>(d1, 256, 18);
    zero_halo_t<unsigned short><<<nblk(128L * 34 * 34 * 34), blk, 0, stream>>>(d2, 128, 34);

    // ---- decoder (MFMA) per batch ----
    for (int b = 0; b < 2; ++b) {
        const unsigned short* qb = qp + (long)b * 256 * 1000;
        float* outb = out + (long)b * 3 * 226981;
        convt_mfma<8, 1, unsigned short><<<dim3(8 * 8 * 4), blk, 0, stream>>>(
            qb, Ap1, dec_b1, d1, 256, 256);
        convt_mfma<16, 1, unsigned short><<<dim3(8 * 64 * 2), blk, 0, stream>>>(
            d1, Ap2, dec_b2, d2, 256, 128);
        convt_mfma<32, 0, float><<<dim3(8 * 512), blk, 0, stream>>>(
            d2, Ap3, dec_b3, d3, 128, 64);
        conv_dec4_mfma<<<dim3(61 * 61), blk, 0, stream>>>(d3, Aw4, dec_b4, outb);
    }
}